// Round 2
// baseline (9038.823 us; speedup 1.0000x reference)
//
#include <hip/hip_runtime.h>
#include <math.h>

constexpr int Bb = 32, Nn = 2048;
constexpr int S1 = 512, K1 = 48;
constexpr int S2 = 128, K2 = 64;

#define DEVI __device__ __forceinline__

// Exact (non-FMA-contracted) squared distance, matches numpy ((dx^2+dy^2)+dz^2) fp32.
DEVI float sq3(float dx, float dy, float dz) {
    return __fadd_rn(__fadd_rn(__fmul_rn(dx, dx), __fmul_rn(dy, dy)), __fmul_rn(dz, dz));
}

// pc (B,3,N) -> xyz (B,N,3)
__global__ void k_transpose(const float* __restrict__ pc, float* __restrict__ xyz) {
    int i = blockIdx.x * blockDim.x + threadIdx.x;
    if (i >= Bb * Nn) return;
    int b = i / Nn;
    const float* s = pc + (size_t)b * 3 * Nn + (i % Nn);
    float* d = xyz + (size_t)i * 3;
    d[0] = s[0];
    d[1] = s[Nn];
    d[2] = s[2 * Nn];
}

// Farthest point sampling: one block per batch. Writes selected coords (b,npoint,3).
// Exact fp32 distances; argmax = first occurrence (strict >, index tie-break).
__global__ void k_fps(const float* __restrict__ pts, int n, int npoint,
                      float* __restrict__ sel) {
    __shared__ float px[2048], py[2048], pz[2048], dist[2048];
    __shared__ float rv[256];
    __shared__ int ri[256];
    __shared__ int s_last;
    int b = blockIdx.x, tid = threadIdx.x;
    const float* base = pts + (size_t)b * n * 3;
    for (int j = tid; j < n; j += 256) {
        px[j] = base[j * 3 + 0];
        py[j] = base[j * 3 + 1];
        pz[j] = base[j * 3 + 2];
        dist[j] = 1e10f;
    }
    if (tid == 0) {
        s_last = 0;
        float* o = sel + (size_t)b * npoint * 3;
        o[0] = base[0]; o[1] = base[1]; o[2] = base[2];
    }
    __syncthreads();
    for (int i = 1; i < npoint; i++) {
        int last = s_last;
        float lx = px[last], ly = py[last], lz = pz[last];
        float bv = -1.0f;
        int bi = 0;
        for (int j = tid; j < n; j += 256) {
            float d = sq3(px[j] - lx, py[j] - ly, pz[j] - lz);
            float dd = fminf(dist[j], d);
            dist[j] = dd;
            if (dd > bv) { bv = dd; bi = j; }
        }
        rv[tid] = bv; ri[tid] = bi;
        __syncthreads();
        for (int off = 128; off > 0; off >>= 1) {
            if (tid < off) {
                float ov = rv[tid + off]; int oi = ri[tid + off];
                if (ov > rv[tid] || (ov == rv[tid] && oi < ri[tid])) { rv[tid] = ov; ri[tid] = oi; }
            }
            __syncthreads();
        }
        if (tid == 0) {
            int sp = ri[0];
            s_last = sp;
            float* o = sel + ((size_t)b * npoint + i) * 3;
            o[0] = px[sp]; o[1] = py[sp]; o[2] = pz[sp];
        }
        __syncthreads();
    }
}

// Ball query: thread per (b,center). First nsample ascending indices with d2<r2, pad first.
__global__ void k_ballquery(const float* __restrict__ src, const float* __restrict__ ctr,
                            int n, int m, int nsample, float r2, int* __restrict__ out) {
    int i = blockIdx.x * blockDim.x + threadIdx.x;
    if (i >= Bb * m) return;
    int b = i / m;
    const float* sb = src + (size_t)b * n * 3;
    float cx = ctr[(size_t)i * 3 + 0];
    float cy = ctr[(size_t)i * 3 + 1];
    float cz = ctr[(size_t)i * 3 + 2];
    int* ob = out + (size_t)i * nsample;
    int cnt = 0;
    for (int j = 0; j < n && cnt < nsample; j++) {
        float d2 = sq3(sb[j * 3 + 0] - cx, sb[j * 3 + 1] - cy, sb[j * 3 + 2] - cz);
        if (d2 < r2) ob[cnt++] = j;
    }
    int first = (cnt > 0) ? ob[0] : 0;
    for (int k = cnt; k < nsample; k++) ob[k] = first;
}

__global__ void k_zero_stats(double* dsum, double* dsq, int O) {
    int i = blockIdx.x * blockDim.x + threadIdx.x;
    if (i < O) { dsum[i] = 0.0; dsq[i] = 0.0; }
}

__global__ void k_finalize(const double* __restrict__ dsum, const double* __restrict__ dsq,
                           const float* __restrict__ g, float* __restrict__ mean,
                           float* __restrict__ scale, int O, double inv_count) {
    int o = blockIdx.x * blockDim.x + threadIdx.x;
    if (o < O) {
        double m = dsum[o] * inv_count;
        double v = dsq[o] * inv_count - m * m;
        mean[o] = (float)m;
        scale[o] = (float)((double)g[o] / sqrt(v + 1e-5));
    }
}

// ---- Stage 1: block per (b,s). MODE 0: stats y1a; 1: stats y1b; 2: maxpool -> f1 ----
template <int MODE>
__global__ __launch_bounds__(256)
void k_stage1(const float* __restrict__ xyz, const float* __restrict__ xyz1,
              const int* __restrict__ ni1, const float* __restrict__ w1a,
              const float* __restrict__ m1a, const float* __restrict__ s1a,
              const float* __restrict__ beta1a, const float* __restrict__ w1b,
              double* __restrict__ dsum, double* __restrict__ dsq,
              const float* __restrict__ m1b, const float* __restrict__ s1b,
              const float* __restrict__ beta1b, float* __restrict__ f1) {
    __shared__ float x1[K1 * 64];     // 12 KB
    __shared__ float wls[64 * 128];   // w1b transposed [c][o], 32 KB
    __shared__ float red[256], red2[256];
    int t = threadIdx.x;
    if (MODE >= 1) {
        for (int idx = t; idx < 64 * 128; idx += 256)
            wls[idx] = w1b[(idx & 127) * 64 + (idx >> 7)];
        __syncthreads();
    }
    float ls = 0.f, lsq = 0.f;
    for (int bs = blockIdx.x; bs < Bb * S1; bs += gridDim.x) {
        int b = bs >> 9;
        float cx = xyz1[bs * 3 + 0], cy = xyz1[bs * 3 + 1], cz = xyz1[bs * 3 + 2];
        // Phase A: y1a (and x1 for MODE>=1)
        for (int idx = t; idx < K1 * 64; idx += 256) {
            int k = idx >> 6, c = idx & 63;
            int j = ni1[bs * K1 + k];
            const float* g = xyz + ((size_t)b * Nn + j) * 3;
            float gx = g[0], gy = g[1], gz = g[2];
            const float* w = w1a + c * 6;
            float y = (gx - cx) * w[0] + (gy - cy) * w[1] + (gz - cz) * w[2]
                    + gx * w[3] + gy * w[4] + gz * w[5];
            if (MODE == 0) { ls += y; lsq += y * y; }
            else x1[idx] = fmaxf((y - m1a[c]) * s1a[c] + beta1a[c], 0.f);
        }
        if (MODE >= 1) {
            __syncthreads();
            int o = t & 127, half = t >> 7;
            float mx = 0.f;
            for (int k = half * 24; k < half * 24 + 24; ++k) {
                const float* xp = x1 + k * 64;
                float acc = 0.f;
                #pragma unroll
                for (int c = 0; c < 64; ++c) acc = fmaf(xp[c], wls[c * 128 + o], acc);
                if (MODE == 1) { ls += acc; lsq += acc * acc; }
                else mx = fmaxf(mx, fmaxf((acc - m1b[o]) * s1b[o] + beta1b[o], 0.f));
            }
            if (MODE == 2) {
                red[t] = mx;
                __syncthreads();
                if (t < 128) f1[(size_t)bs * 128 + t] = fmaxf(red[t], red[t + 128]);
            }
            __syncthreads();  // protect x1/red for next iteration
        }
    }
    if (MODE == 0) {
        red[t] = ls; red2[t] = lsq;
        __syncthreads();
        if (t < 64) {
            double S = (double)red[t] + red[t + 64] + red[t + 128] + red[t + 192];
            double Q = (double)red2[t] + red2[t + 64] + red2[t + 128] + red2[t + 192];
            atomicAdd(&dsum[t], S); atomicAdd(&dsq[t], Q);
        }
    } else if (MODE == 1) {
        red[t] = ls; red2[t] = lsq;
        __syncthreads();
        if (t < 128) {
            atomicAdd(&dsum[t], (double)red[t] + red[t + 128]);
            atomicAdd(&dsq[t], (double)red2[t] + red2[t + 128]);
        }
    }
}

// ---- Stage 2: block per (b,s). MODE 0: stats y2a; 1: stats y2b; 2: maxpool -> f2 ----
template <int MODE>
__global__ __launch_bounds__(256)
void k_stage2(const float* __restrict__ xyz1, const float* __restrict__ xyz2,
              const int* __restrict__ ni2, const float* __restrict__ f1,
              const float* __restrict__ w2a,
              const float* __restrict__ m2a, const float* __restrict__ s2a,
              const float* __restrict__ beta2a, const float* __restrict__ w2b,
              double* __restrict__ dsum, double* __restrict__ dsq,
              const float* __restrict__ m2b, const float* __restrict__ s2b,
              const float* __restrict__ beta2b, float* __restrict__ f2) {
    __shared__ float ft[K2 * 134];  // gather tile, reused as x2[k*128+o]; 34.3 KB
    __shared__ float ssum[128], ssq[128];
    int t = threadIdx.x;
    if (MODE == 0) {
        if (t < 128) { ssum[t] = 0.f; ssq[t] = 0.f; }
        __syncthreads();
    }
    float ls0 = 0.f, lsq0 = 0.f, ls1 = 0.f, lsq1 = 0.f;
    for (int bs = blockIdx.x; bs < Bb * S2; bs += gridDim.x) {
        int b = bs >> 7;
        float cx = xyz2[bs * 3 + 0], cy = xyz2[bs * 3 + 1], cz = xyz2[bs * 3 + 2];
        // A1: gather feat2 tile [k][134]
        for (int idx = t; idx < K2 * 134; idx += 256) {
            int k = idx / 134, c = idx - k * 134;
            int j = ni2[bs * K2 + k];
            const float* p1 = xyz1 + ((size_t)b * S1 + j) * 3;
            float v;
            if (c < 3)      v = p1[c] - (c == 0 ? cx : (c == 1 ? cy : cz));
            else if (c < 6) v = p1[c - 3];
            else            v = f1[((size_t)b * S1 + j) * 128 + (c - 6)];
            ft[idx] = v;
        }
        __syncthreads();
        // A2: y2a (stats) or x2 into regs
        float x2v[32];
        for (int i = 0; i < 32; ++i) {
            int idx = t + i * 256;
            const float* xr = ft + (idx >> 7) * 134;
            const float* wr = w2a + (idx & 127) * 134;
            float acc = 0.f;
            for (int c = 0; c < 134; ++c) acc = fmaf(xr[c], wr[c], acc);
            if (MODE == 0) { ls0 += acc; lsq0 += acc * acc; }
            else {
                int o = idx & 127;
                x2v[i] = fmaxf((acc - m2a[o]) * s2a[o] + beta2a[o], 0.f);
            }
        }
        __syncthreads();  // done reading gather tile
        if (MODE >= 1) {
            // A3: x2 -> LDS, layout [k*128+o] == idx
            for (int i = 0; i < 32; ++i) ft[t + i * 256] = x2v[i];
            __syncthreads();
            // B: y2b = x2 @ w2b^T; thread owns o2 = {t, t+256}; k tiled by 16
            float mx0 = 0.f, mx1 = 0.f;
            for (int kt = 0; kt < 4; ++kt) {
                float acc0[16], acc1[16];
                #pragma unroll
                for (int kk = 0; kk < 16; ++kk) { acc0[kk] = 0.f; acc1[kk] = 0.f; }
                const float* w0 = w2b + (size_t)t * 128;
                const float* w1 = w2b + (size_t)(t + 256) * 128;
                const float* xb = ft + kt * 16 * 128;
                for (int c = 0; c < 128; ++c) {
                    float wv0 = w0[c], wv1 = w1[c];
                    #pragma unroll
                    for (int kk = 0; kk < 16; ++kk) {
                        float xv = xb[kk * 128 + c];
                        acc0[kk] = fmaf(xv, wv0, acc0[kk]);
                        acc1[kk] = fmaf(xv, wv1, acc1[kk]);
                    }
                }
                #pragma unroll
                for (int kk = 0; kk < 16; ++kk) {
                    float y0 = acc0[kk], y1 = acc1[kk];
                    if (MODE == 1) {
                        ls0 += y0; lsq0 += y0 * y0;
                        ls1 += y1; lsq1 += y1 * y1;
                    } else {
                        mx0 = fmaxf(mx0, fmaxf((y0 - m2b[t]) * s2b[t] + beta2b[t], 0.f));
                        mx1 = fmaxf(mx1, fmaxf((y1 - m2b[t + 256]) * s2b[t + 256] + beta2b[t + 256], 0.f));
                    }
                }
            }
            if (MODE == 2) {
                f2[(size_t)bs * 512 + t] = mx0;
                f2[(size_t)bs * 512 + t + 256] = mx1;
            }
            __syncthreads();  // protect ft for next iteration
        }
    }
    if (MODE == 0) {
        atomicAdd(&ssum[t & 127], ls0);
        atomicAdd(&ssq[t & 127], lsq0);
        __syncthreads();
        if (t < 128) {
            atomicAdd(&dsum[t], (double)ssum[t]);
            atomicAdd(&dsq[t], (double)ssq[t]);
        }
    } else if (MODE == 1) {
        atomicAdd(&dsum[t], (double)ls0);
        atomicAdd(&dsq[t], (double)lsq0);
        atomicAdd(&dsum[t + 256], (double)ls1);
        atomicAdd(&dsq[t + 256], (double)lsq1);
    }
}

// ---- Stage 3: block per (b, o-half); thread per o. MODE 1: stats; 2: max -> out ----
template <int MODE>
__global__ __launch_bounds__(256)
void k_stage3(const float* __restrict__ xyz2, const float* __restrict__ f2,
              const float* __restrict__ w3, double* __restrict__ dsum,
              double* __restrict__ dsq, const float* __restrict__ m3,
              const float* __restrict__ s3, const float* __restrict__ beta3,
              float* __restrict__ out) {
    int b = blockIdx.x >> 1;
    int o = ((blockIdx.x & 1) << 8) + threadIdx.x;
    const float* wr = w3 + (size_t)o * 515;
    float ls = 0.f, lsq = 0.f, mx = 0.f;
    for (int st = 0; st < 8; ++st) {
        float acc[16];
        #pragma unroll
        for (int kk = 0; kk < 16; ++kk) acc[kk] = 0.f;
        for (int c = 0; c < 515; ++c) {
            float wv = wr[c];
            #pragma unroll
            for (int kk = 0; kk < 16; ++kk) {
                int row = b * S2 + st * 16 + kk;
                float xv = (c < 3) ? xyz2[row * 3 + c] : f2[(size_t)row * 512 + (c - 3)];
                acc[kk] = fmaf(xv, wv, acc[kk]);
            }
        }
        #pragma unroll
        for (int kk = 0; kk < 16; ++kk) {
            float y = acc[kk];
            if (MODE == 1) { ls += y; lsq += y * y; }
            else mx = fmaxf(mx, fmaxf((y - m3[o]) * s3[o] + beta3[o], 0.f));
        }
    }
    if (MODE == 1) {
        atomicAdd(&dsum[o], (double)ls);
        atomicAdd(&dsq[o], (double)lsq);
    } else {
        out[(size_t)b * 512 + o] = mx;
    }
}

static inline size_t align256(size_t x) { return (x + 255) & ~(size_t)255; }

extern "C" void kernel_launch(void* const* d_in, const int* in_sizes, int n_in,
                              void* d_out, int out_size, void* d_ws, size_t ws_size,
                              hipStream_t stream) {
    const float* pc  = (const float*)d_in[0];
    const float* w1a = (const float*)d_in[1];
    const float* g1a = (const float*)d_in[2];
    const float* b1a = (const float*)d_in[3];
    const float* w1b = (const float*)d_in[4];
    const float* g1b = (const float*)d_in[5];
    const float* b1b = (const float*)d_in[6];
    const float* w2a = (const float*)d_in[7];
    const float* g2a = (const float*)d_in[8];
    const float* b2a = (const float*)d_in[9];
    const float* w2b = (const float*)d_in[10];
    const float* g2b = (const float*)d_in[11];
    const float* b2b = (const float*)d_in[12];
    const float* w3  = (const float*)d_in[13];
    const float* g3  = (const float*)d_in[14];
    const float* b3  = (const float*)d_in[15];
    float* out = (float*)d_out;

    char* ws = (char*)d_ws;
    size_t off = 0;
    auto alloc = [&](size_t bytes) { void* p = ws + off; off += align256(bytes); return p; };

    float* xyz   = (float*)alloc(sizeof(float) * Bb * Nn * 3);
    float* xyz1  = (float*)alloc(sizeof(float) * Bb * S1 * 3);
    float* xyz2  = (float*)alloc(sizeof(float) * Bb * S2 * 3);
    int*   ni1   = (int*)alloc(sizeof(int) * Bb * S1 * K1);
    int*   ni2   = (int*)alloc(sizeof(int) * Bb * S2 * K2);
    float* f1    = (float*)alloc(sizeof(float) * (size_t)Bb * S1 * 128);
    float* f2    = (float*)alloc(sizeof(float) * (size_t)Bb * S2 * 512);
    double* dsum = (double*)alloc(sizeof(double) * 512);
    double* dsq  = (double*)alloc(sizeof(double) * 512);
    float* m1a = (float*)alloc(sizeof(float) * 64);
    float* s1a = (float*)alloc(sizeof(float) * 64);
    float* m1b = (float*)alloc(sizeof(float) * 128);
    float* s1b = (float*)alloc(sizeof(float) * 128);
    float* m2a = (float*)alloc(sizeof(float) * 128);
    float* s2a = (float*)alloc(sizeof(float) * 128);
    float* m2b = (float*)alloc(sizeof(float) * 512);
    float* s2b = (float*)alloc(sizeof(float) * 512);
    float* m3  = (float*)alloc(sizeof(float) * 512);
    float* s3  = (float*)alloc(sizeof(float) * 512);
    // total ws usage ~22 MB (round-0's 297 MB arena was the crash suspect)

    // ---- Stage 1 ----
    k_transpose<<<(Bb * Nn + 255) / 256, 256, 0, stream>>>(pc, xyz);
    k_fps<<<Bb, 256, 0, stream>>>(xyz, Nn, S1, xyz1);
    k_ballquery<<<(Bb * S1 + 255) / 256, 256, 0, stream>>>(xyz, xyz1, Nn, S1, K1,
                                                           (float)(0.23 * 0.23), ni1);
    k_zero_stats<<<2, 256, 0, stream>>>(dsum, dsq, 512);
    k_stage1<0><<<2048, 256, 0, stream>>>(xyz, xyz1, ni1, w1a, m1a, s1a, b1a, w1b,
                                          dsum, dsq, m1b, s1b, b1b, f1);
    k_finalize<<<2, 256, 0, stream>>>(dsum, dsq, g1a, m1a, s1a, 64,
                                      1.0 / ((double)Bb * S1 * K1));
    k_zero_stats<<<2, 256, 0, stream>>>(dsum, dsq, 512);
    k_stage1<1><<<2048, 256, 0, stream>>>(xyz, xyz1, ni1, w1a, m1a, s1a, b1a, w1b,
                                          dsum, dsq, m1b, s1b, b1b, f1);
    k_finalize<<<2, 256, 0, stream>>>(dsum, dsq, g1b, m1b, s1b, 128,
                                      1.0 / ((double)Bb * S1 * K1));
    k_stage1<2><<<Bb * S1, 256, 0, stream>>>(xyz, xyz1, ni1, w1a, m1a, s1a, b1a, w1b,
                                             dsum, dsq, m1b, s1b, b1b, f1);
    // ---- Stage 2 ----
    k_fps<<<Bb, 256, 0, stream>>>(xyz1, S1, S2, xyz2);
    k_ballquery<<<(Bb * S2 + 255) / 256, 256, 0, stream>>>(xyz1, xyz2, S1, S2, K2,
                                                           (float)(0.32 * 0.32), ni2);
    k_zero_stats<<<2, 256, 0, stream>>>(dsum, dsq, 512);
    k_stage2<0><<<1024, 256, 0, stream>>>(xyz1, xyz2, ni2, f1, w2a, m2a, s2a, b2a, w2b,
                                          dsum, dsq, m2b, s2b, b2b, f2);
    k_finalize<<<2, 256, 0, stream>>>(dsum, dsq, g2a, m2a, s2a, 128,
                                      1.0 / ((double)Bb * S2 * K2));
    k_zero_stats<<<2, 256, 0, stream>>>(dsum, dsq, 512);
    k_stage2<1><<<1024, 256, 0, stream>>>(xyz1, xyz2, ni2, f1, w2a, m2a, s2a, b2a, w2b,
                                          dsum, dsq, m2b, s2b, b2b, f2);
    k_finalize<<<2, 256, 0, stream>>>(dsum, dsq, g2b, m2b, s2b, 512,
                                      1.0 / ((double)Bb * S2 * K2));
    k_stage2<2><<<Bb * S2, 256, 0, stream>>>(xyz1, xyz2, ni2, f1, w2a, m2a, s2a, b2a, w2b,
                                             dsum, dsq, m2b, s2b, b2b, f2);
    // ---- Stage 3 ----
    k_zero_stats<<<2, 256, 0, stream>>>(dsum, dsq, 512);
    k_stage3<1><<<Bb * 2, 256, 0, stream>>>(xyz2, f2, w3, dsum, dsq, m3, s3, b3, out);
    k_finalize<<<2, 256, 0, stream>>>(dsum, dsq, g3, m3, s3, 512,
                                      1.0 / ((double)Bb * S2));
    k_stage3<2><<<Bb * 2, 256, 0, stream>>>(xyz2, f2, w3, dsum, dsq, m3, s3, b3, out);
}

// Round 3
// 3545.025 us; speedup vs baseline: 2.5497x; 2.5497x over previous
//
#include <hip/hip_runtime.h>
#include <math.h>

constexpr int Bb = 32, Nn = 2048;
constexpr int S1 = 512, K1 = 48;
constexpr int S2 = 128, K2 = 64;

#define DEVI __device__ __forceinline__

// Exact (non-FMA-contracted) squared distance, matches numpy ((dx^2+dy^2)+dz^2) fp32.
DEVI float sq3(float dx, float dy, float dz) {
    return __fadd_rn(__fadd_rn(__fmul_rn(dx, dx), __fmul_rn(dy, dy)), __fmul_rn(dz, dz));
}

// pc (B,3,N) -> xyz (B,N,3)
__global__ void k_transpose(const float* __restrict__ pc, float* __restrict__ xyz) {
    int i = blockIdx.x * blockDim.x + threadIdx.x;
    if (i >= Bb * Nn) return;
    int b = i / Nn;
    const float* s = pc + (size_t)b * 3 * Nn + (i % Nn);
    float* d = xyz + (size_t)i * 3;
    d[0] = s[0];
    d[1] = s[Nn];
    d[2] = s[2 * Nn];
}

// Farthest point sampling: one block per batch. Exact fp32; argmax first-occurrence.
__global__ void k_fps(const float* __restrict__ pts, int n, int npoint,
                      float* __restrict__ sel) {
    __shared__ float px[2048], py[2048], pz[2048], dist[2048];
    __shared__ float rv[256];
    __shared__ int ri[256];
    __shared__ int s_last;
    int b = blockIdx.x, tid = threadIdx.x;
    const float* base = pts + (size_t)b * n * 3;
    for (int j = tid; j < n; j += 256) {
        px[j] = base[j * 3 + 0];
        py[j] = base[j * 3 + 1];
        pz[j] = base[j * 3 + 2];
        dist[j] = 1e10f;
    }
    if (tid == 0) {
        s_last = 0;
        float* o = sel + (size_t)b * npoint * 3;
        o[0] = base[0]; o[1] = base[1]; o[2] = base[2];
    }
    __syncthreads();
    for (int i = 1; i < npoint; i++) {
        int last = s_last;
        float lx = px[last], ly = py[last], lz = pz[last];
        float bv = -1.0f;
        int bi = 0;
        for (int j = tid; j < n; j += 256) {
            float d = sq3(px[j] - lx, py[j] - ly, pz[j] - lz);
            float dd = fminf(dist[j], d);
            dist[j] = dd;
            if (dd > bv) { bv = dd; bi = j; }
        }
        rv[tid] = bv; ri[tid] = bi;
        __syncthreads();
        for (int off = 128; off > 0; off >>= 1) {
            if (tid < off) {
                float ov = rv[tid + off]; int oi = ri[tid + off];
                if (ov > rv[tid] || (ov == rv[tid] && oi < ri[tid])) { rv[tid] = ov; ri[tid] = oi; }
            }
            __syncthreads();
        }
        if (tid == 0) {
            int sp = ri[0];
            s_last = sp;
            float* o = sel + ((size_t)b * npoint + i) * 3;
            o[0] = px[sp]; o[1] = py[sp]; o[2] = pz[sp];
        }
        __syncthreads();
    }
}

// Ball query: thread per (b,center).
__global__ void k_ballquery(const float* __restrict__ src, const float* __restrict__ ctr,
                            int n, int m, int nsample, float r2, int* __restrict__ out) {
    int i = blockIdx.x * blockDim.x + threadIdx.x;
    if (i >= Bb * m) return;
    int b = i / m;
    const float* sb = src + (size_t)b * n * 3;
    float cx = ctr[(size_t)i * 3 + 0];
    float cy = ctr[(size_t)i * 3 + 1];
    float cz = ctr[(size_t)i * 3 + 2];
    int* ob = out + (size_t)i * nsample;
    int cnt = 0;
    for (int j = 0; j < n && cnt < nsample; j++) {
        float d2 = sq3(sb[j * 3 + 0] - cx, sb[j * 3 + 1] - cy, sb[j * 3 + 2] - cz);
        if (d2 < r2) ob[cnt++] = j;
    }
    int first = (cnt > 0) ? ob[0] : 0;
    for (int k = cnt; k < nsample; k++) ob[k] = first;
}

__global__ void k_zero_stats(double* dsum, double* dsq, int O) {
    int i = blockIdx.x * blockDim.x + threadIdx.x;
    if (i < O) { dsum[i] = 0.0; dsq[i] = 0.0; }
}

__global__ void k_finalize(const double* __restrict__ dsum, const double* __restrict__ dsq,
                           const float* __restrict__ g, float* __restrict__ mean,
                           float* __restrict__ scale, int O, double inv_count) {
    int o = blockIdx.x * blockDim.x + threadIdx.x;
    if (o < O) {
        double m = dsum[o] * inv_count;
        double v = dsq[o] * inv_count - m * m;
        mean[o] = (float)m;
        scale[o] = (float)((double)g[o] / sqrt(v + 1e-5));
    }
}

// Apply norm+relu to pooled minmax (in-place capable: f may alias gmx).
__global__ void k_applyMM(const float* __restrict__ gmx, const float* __restrict__ gmn,
                          const float* __restrict__ m, const float* __restrict__ s,
                          const float* __restrict__ beta, float* __restrict__ f,
                          long long total, int O) {
    long long i = (long long)blockIdx.x * blockDim.x + threadIdx.x;
    if (i >= total) return;
    int o = (int)(i % O);
    float sc = s[o];
    float pick = (sc >= 0.f) ? gmx[i] : gmn[i];
    f[i] = fmaxf((pick - m[o]) * sc + beta[o], 0.f);
}

// ---------------- Stage 1 ----------------
// Stats of y1a (C=6 -> O=64) over all (b,s,k).
__global__ __launch_bounds__(256)
void k_s1_statsA(const float* __restrict__ xyz, const float* __restrict__ xyz1,
                 const int* __restrict__ ni1, const float* __restrict__ w1a,
                 double* __restrict__ dsum, double* __restrict__ dsq) {
    __shared__ float red[256], red2[256];
    int t = threadIdx.x;
    float ls = 0.f, lsq = 0.f;
    for (int bs = blockIdx.x; bs < Bb * S1; bs += gridDim.x) {
        int b = bs >> 9;
        float cx = xyz1[bs * 3 + 0], cy = xyz1[bs * 3 + 1], cz = xyz1[bs * 3 + 2];
        for (int idx = t; idx < K1 * 64; idx += 256) {
            int k = idx >> 6, c = idx & 63;
            int j = ni1[bs * K1 + k];
            const float* g = xyz + ((size_t)b * Nn + j) * 3;
            float gx = g[0], gy = g[1], gz = g[2];
            const float* w = w1a + c * 6;
            float y = (gx - cx) * w[0] + (gy - cy) * w[1] + (gz - cz) * w[2]
                    + gx * w[3] + gy * w[4] + gz * w[5];
            ls += y; lsq += y * y;
        }
    }
    red[t] = ls; red2[t] = lsq;
    __syncthreads();
    if (t < 64) {
        double S = (double)red[t] + red[t + 64] + red[t + 128] + red[t + 192];
        double Q = (double)red2[t] + red2[t + 64] + red2[t + 128] + red2[t + 192];
        atomicAdd(&dsum[t], S); atomicAdd(&dsq[t], Q);
    }
}

// Main stage-1: x1 = relu(norm(y1a)); y1b (64->128): stats + per-(bs,o) max/min.
// Weights w1b held in registers (lane owns o), x broadcast from LDS.
__global__ __launch_bounds__(256)
void k_s1_main(const float* __restrict__ xyz, const float* __restrict__ xyz1,
               const int* __restrict__ ni1, const float* __restrict__ w1a,
               const float* __restrict__ m1a, const float* __restrict__ s1a,
               const float* __restrict__ beta1a, const float* __restrict__ w1b,
               double* __restrict__ dsum, double* __restrict__ dsq,
               float* __restrict__ gmx, float* __restrict__ gmn) {
    __shared__ float x1[K1 * 64];  // 12.3 KB
    __shared__ float red[256], red2[256];
    int t = threadIdx.x;
    int o = t & 127, half = t >> 7;
    float wb[64];
    #pragma unroll
    for (int c = 0; c < 64; ++c) wb[c] = w1b[(size_t)o * 64 + c];
    float ls = 0.f, lsq = 0.f;
    for (int bs = blockIdx.x; bs < Bb * S1; bs += gridDim.x) {
        int b = bs >> 9;
        float cx = xyz1[bs * 3 + 0], cy = xyz1[bs * 3 + 1], cz = xyz1[bs * 3 + 2];
        for (int idx = t; idx < K1 * 64; idx += 256) {
            int k = idx >> 6, c = idx & 63;
            int j = ni1[bs * K1 + k];
            const float* g = xyz + ((size_t)b * Nn + j) * 3;
            float gx = g[0], gy = g[1], gz = g[2];
            const float* w = w1a + c * 6;
            float y = (gx - cx) * w[0] + (gy - cy) * w[1] + (gz - cz) * w[2]
                    + gx * w[3] + gy * w[4] + gz * w[5];
            x1[idx] = fmaxf((y - m1a[c]) * s1a[c] + beta1a[c], 0.f);
        }
        __syncthreads();
        float mxv = -1e30f, mnv = 1e30f;
        for (int k = half * 24; k < half * 24 + 24; ++k) {
            const float* xp = &x1[k * 64];
            float p0 = 0.f, p1 = 0.f;
            #pragma unroll
            for (int j = 0; j < 16; j += 2) {
                float4 a = *(const float4*)(xp + 4 * j);
                float4 c4 = *(const float4*)(xp + 4 * j + 4);
                p0 = fmaf(a.x, wb[4 * j + 0], p0);
                p0 = fmaf(a.y, wb[4 * j + 1], p0);
                p0 = fmaf(a.z, wb[4 * j + 2], p0);
                p0 = fmaf(a.w, wb[4 * j + 3], p0);
                p1 = fmaf(c4.x, wb[4 * j + 4], p1);
                p1 = fmaf(c4.y, wb[4 * j + 5], p1);
                p1 = fmaf(c4.z, wb[4 * j + 6], p1);
                p1 = fmaf(c4.w, wb[4 * j + 7], p1);
            }
            float y = p0 + p1;
            ls += y; lsq += y * y;
            mxv = fmaxf(mxv, y); mnv = fminf(mnv, y);
        }
        red[t] = mxv; red2[t] = mnv;
        __syncthreads();
        if (t < 128) {
            gmx[(size_t)bs * 128 + t] = fmaxf(red[t], red[t + 128]);
            gmn[(size_t)bs * 128 + t] = fminf(red2[t], red2[t + 128]);
        }
        __syncthreads();
    }
    red[t] = ls; red2[t] = lsq;
    __syncthreads();
    if (t < 128) {
        atomicAdd(&dsum[t], (double)red[t] + red[t + 128]);
        atomicAdd(&dsq[t], (double)red2[t] + red2[t + 128]);
    }
}

// ---------------- Stage 2 ----------------
constexpr int FT_LD = 136;  // padded row (134 real + 2 zero), 16B-aligned stride

DEVI void s2_gather(int t, int nthr, int bs, const float* xyz1, const float* xyz2,
                    const int* ni2, const float* f1, float* ft) {
    int b = bs >> 7;
    float cx = xyz2[bs * 3 + 0], cy = xyz2[bs * 3 + 1], cz = xyz2[bs * 3 + 2];
    for (int idx = t; idx < K2 * 134; idx += nthr) {
        int k = idx / 134, c = idx - k * 134;
        int j = ni2[bs * K2 + k];
        const float* p1 = xyz1 + ((size_t)b * S1 + j) * 3;
        float v;
        if (c < 3)      v = p1[c] - (c == 0 ? cx : (c == 1 ? cy : cz));
        else if (c < 6) v = p1[c - 3];
        else            v = f1[((size_t)b * S1 + j) * 128 + (c - 6)];
        ft[k * FT_LD + c] = v;
    }
    if (t < 128) ft[(t >> 1) * FT_LD + 134 + (t & 1)] = 0.f;
}

// Stats of y2a (C=134 -> O=128).
__global__ __launch_bounds__(256)
void k_s2_statsA(const float* __restrict__ xyz1, const float* __restrict__ xyz2,
                 const int* __restrict__ ni2, const float* __restrict__ f1,
                 const float* __restrict__ w2a,
                 double* __restrict__ dsum, double* __restrict__ dsq) {
    __shared__ float ft[K2 * FT_LD];  // 34.8 KB
    __shared__ float red[256], red2[256];
    int t = threadIdx.x;
    int o = t & 127, kh = t >> 7;  // kh in {0,1}: k = kh*32 + kk
    float ls = 0.f, lsq = 0.f;
    for (int bs = blockIdx.x; bs < Bb * S2; bs += gridDim.x) {
        s2_gather(t, 256, bs, xyz1, xyz2, ni2, f1, ft);
        __syncthreads();
        float acc[32];
        #pragma unroll
        for (int kk = 0; kk < 32; ++kk) acc[kk] = 0.f;
        for (int ct = 0; ct < 4; ++ct) {
            float wr[32];
            #pragma unroll
            for (int i = 0; i < 32; ++i) wr[i] = w2a[(size_t)o * 134 + ct * 32 + i];
            #pragma unroll
            for (int kk = 0; kk < 32; ++kk) {
                const float* xr = &ft[(kh * 32 + kk) * FT_LD + ct * 32];
                #pragma unroll
                for (int j = 0; j < 8; ++j) {
                    float4 x = *(const float4*)(xr + 4 * j);
                    acc[kk] = fmaf(x.x, wr[4 * j + 0], acc[kk]);
                    acc[kk] = fmaf(x.y, wr[4 * j + 1], acc[kk]);
                    acc[kk] = fmaf(x.z, wr[4 * j + 2], acc[kk]);
                    acc[kk] = fmaf(x.w, wr[4 * j + 3], acc[kk]);
                }
            }
        }
        {  // tail c = 128..135 (134,135 zero-padded)
            float wr[8];
            #pragma unroll
            for (int i = 0; i < 8; ++i) wr[i] = (i < 6) ? w2a[(size_t)o * 134 + 128 + i] : 0.f;
            #pragma unroll
            for (int kk = 0; kk < 32; ++kk) {
                const float* xr = &ft[(kh * 32 + kk) * FT_LD + 128];
                #pragma unroll
                for (int j = 0; j < 2; ++j) {
                    float4 x = *(const float4*)(xr + 4 * j);
                    acc[kk] = fmaf(x.x, wr[4 * j + 0], acc[kk]);
                    acc[kk] = fmaf(x.y, wr[4 * j + 1], acc[kk]);
                    acc[kk] = fmaf(x.z, wr[4 * j + 2], acc[kk]);
                    acc[kk] = fmaf(x.w, wr[4 * j + 3], acc[kk]);
                }
            }
        }
        #pragma unroll
        for (int kk = 0; kk < 32; ++kk) { ls += acc[kk]; lsq += acc[kk] * acc[kk]; }
        __syncthreads();
    }
    red[t] = ls; red2[t] = lsq;
    __syncthreads();
    if (t < 128) {
        atomicAdd(&dsum[t], (double)red[t] + red[t + 128]);
        atomicAdd(&dsq[t], (double)red2[t] + red2[t + 128]);
    }
}

// Main stage-2: recompute y2a -> x2 (LDS), y2b (128->512): stats + per-(bs,o) max/min.
__global__ __launch_bounds__(512)
void k_s2_main(const float* __restrict__ xyz1, const float* __restrict__ xyz2,
               const int* __restrict__ ni2, const float* __restrict__ f1,
               const float* __restrict__ w2a,
               const float* __restrict__ m2a, const float* __restrict__ s2a,
               const float* __restrict__ beta2a, const float* __restrict__ w2b,
               double* __restrict__ dsum, double* __restrict__ dsq,
               float* __restrict__ gmx, float* __restrict__ gmn) {
    __shared__ float ft[K2 * FT_LD];  // 34.8 KB; reused: cols 0..127 become x2
    int t = threadIdx.x;
    int oa = t & 127, kq = t >> 7;  // A-phase: k = kq*16 + kk
    float ls = 0.f, lsq = 0.f;
    for (int bs = blockIdx.x; bs < Bb * S2; bs += gridDim.x) {
        s2_gather(t, 512, bs, xyz1, xyz2, ni2, f1, ft);
        __syncthreads();
        // A: y2a for 16 k's
        float acc[16];
        #pragma unroll
        for (int kk = 0; kk < 16; ++kk) acc[kk] = 0.f;
        for (int ct = 0; ct < 4; ++ct) {
            float wr[32];
            #pragma unroll
            for (int i = 0; i < 32; ++i) wr[i] = w2a[(size_t)oa * 134 + ct * 32 + i];
            #pragma unroll
            for (int kk = 0; kk < 16; ++kk) {
                const float* xr = &ft[(kq * 16 + kk) * FT_LD + ct * 32];
                #pragma unroll
                for (int j = 0; j < 8; ++j) {
                    float4 x = *(const float4*)(xr + 4 * j);
                    acc[kk] = fmaf(x.x, wr[4 * j + 0], acc[kk]);
                    acc[kk] = fmaf(x.y, wr[4 * j + 1], acc[kk]);
                    acc[kk] = fmaf(x.z, wr[4 * j + 2], acc[kk]);
                    acc[kk] = fmaf(x.w, wr[4 * j + 3], acc[kk]);
                }
            }
        }
        {
            float wr[8];
            #pragma unroll
            for (int i = 0; i < 8; ++i) wr[i] = (i < 6) ? w2a[(size_t)oa * 134 + 128 + i] : 0.f;
            #pragma unroll
            for (int kk = 0; kk < 16; ++kk) {
                const float* xr = &ft[(kq * 16 + kk) * FT_LD + 128];
                #pragma unroll
                for (int j = 0; j < 2; ++j) {
                    float4 x = *(const float4*)(xr + 4 * j);
                    acc[kk] = fmaf(x.x, wr[4 * j + 0], acc[kk]);
                    acc[kk] = fmaf(x.y, wr[4 * j + 1], acc[kk]);
                    acc[kk] = fmaf(x.z, wr[4 * j + 2], acc[kk]);
                    acc[kk] = fmaf(x.w, wr[4 * j + 3], acc[kk]);
                }
            }
        }
        float ma = m2a[oa], sa = s2a[oa], ba = beta2a[oa];
        #pragma unroll
        for (int kk = 0; kk < 16; ++kk)
            acc[kk] = fmaxf((acc[kk] - ma) * sa + ba, 0.f);
        __syncthreads();  // all ft reads done
        #pragma unroll
        for (int kk = 0; kk < 16; ++kk) ft[(kq * 16 + kk) * FT_LD + oa] = acc[kk];
        __syncthreads();
        // B: y2b, thread owns o = t (512 outs); k chunked by 32
        float mxv = -1e30f, mnv = 1e30f;
        for (int kb = 0; kb < 64; kb += 32) {
            float acb[32];
            #pragma unroll
            for (int kk = 0; kk < 32; ++kk) acb[kk] = 0.f;
            for (int ct = 0; ct < 4; ++ct) {
                float wr[32];
                #pragma unroll
                for (int i = 0; i < 32; ++i) wr[i] = w2b[(size_t)t * 128 + ct * 32 + i];
                #pragma unroll
                for (int kk = 0; kk < 32; ++kk) {
                    const float* xr = &ft[(kb + kk) * FT_LD + ct * 32];
                    #pragma unroll
                    for (int j = 0; j < 8; ++j) {
                        float4 x = *(const float4*)(xr + 4 * j);
                        acb[kk] = fmaf(x.x, wr[4 * j + 0], acb[kk]);
                        acb[kk] = fmaf(x.y, wr[4 * j + 1], acb[kk]);
                        acb[kk] = fmaf(x.z, wr[4 * j + 2], acb[kk]);
                        acb[kk] = fmaf(x.w, wr[4 * j + 3], acb[kk]);
                    }
                }
            }
            #pragma unroll
            for (int kk = 0; kk < 32; ++kk) {
                float y = acb[kk];
                ls += y; lsq += y * y;
                mxv = fmaxf(mxv, y); mnv = fminf(mnv, y);
            }
        }
        gmx[(size_t)bs * 512 + t] = mxv;
        gmn[(size_t)bs * 512 + t] = mnv;
        __syncthreads();  // before next gather overwrites ft
    }
    atomicAdd(&dsum[t], (double)ls);
    atomicAdd(&dsq[t], (double)lsq);
}

// ---------------- Stage 3 ----------------
constexpr int X3_LD = 520;  // 515 real + 5 zero pad

__global__ __launch_bounds__(512)
void k_s3(const float* __restrict__ xyz2, const float* __restrict__ f2,
          const float* __restrict__ w3, double* __restrict__ dsum,
          double* __restrict__ dsq, float* __restrict__ gmx, float* __restrict__ gmn) {
    __shared__ float xt[16 * X3_LD];  // 33.3 KB
    int b = blockIdx.x >> 3, kc = blockIdx.x & 7;
    int t = threadIdx.x;  // = o
    for (int idx = t; idx < 16 * X3_LD; idx += 512) {
        int rr = idx / X3_LD, c = idx - rr * X3_LD;
        int row = b * S2 + kc * 16 + rr;
        float v;
        if (c < 3)        v = xyz2[row * 3 + c];
        else if (c < 515) v = f2[(size_t)row * 512 + (c - 3)];
        else              v = 0.f;
        xt[idx] = v;
    }
    __syncthreads();
    float acc[16];
    #pragma unroll
    for (int rr = 0; rr < 16; ++rr) acc[rr] = 0.f;
    for (int ct = 0; ct < 16; ++ct) {
        float wr[32];
        #pragma unroll
        for (int i = 0; i < 32; ++i) wr[i] = w3[(size_t)t * 515 + ct * 32 + i];
        #pragma unroll
        for (int rr = 0; rr < 16; ++rr) {
            const float* xr = &xt[rr * X3_LD + ct * 32];
            #pragma unroll
            for (int j = 0; j < 8; ++j) {
                float4 x = *(const float4*)(xr + 4 * j);
                acc[rr] = fmaf(x.x, wr[4 * j + 0], acc[rr]);
                acc[rr] = fmaf(x.y, wr[4 * j + 1], acc[rr]);
                acc[rr] = fmaf(x.z, wr[4 * j + 2], acc[rr]);
                acc[rr] = fmaf(x.w, wr[4 * j + 3], acc[rr]);
            }
        }
    }
    {
        float wr[8];
        #pragma unroll
        for (int i = 0; i < 8; ++i) wr[i] = (i < 3) ? w3[(size_t)t * 515 + 512 + i] : 0.f;
        #pragma unroll
        for (int rr = 0; rr < 16; ++rr) {
            const float* xr = &xt[rr * X3_LD + 512];
            #pragma unroll
            for (int j = 0; j < 2; ++j) {
                float4 x = *(const float4*)(xr + 4 * j);
                acc[rr] = fmaf(x.x, wr[4 * j + 0], acc[rr]);
                acc[rr] = fmaf(x.y, wr[4 * j + 1], acc[rr]);
                acc[rr] = fmaf(x.z, wr[4 * j + 2], acc[rr]);
                acc[rr] = fmaf(x.w, wr[4 * j + 3], acc[rr]);
            }
        }
    }
    float ls = 0.f, lsq = 0.f, mxv = -1e30f, mnv = 1e30f;
    #pragma unroll
    for (int rr = 0; rr < 16; ++rr) {
        float y = acc[rr];
        ls += y; lsq += y * y;
        mxv = fmaxf(mxv, y); mnv = fminf(mnv, y);
    }
    atomicAdd(&dsum[t], (double)ls);
    atomicAdd(&dsq[t], (double)lsq);
    gmx[(size_t)blockIdx.x * 512 + t] = mxv;
    gmn[(size_t)blockIdx.x * 512 + t] = mnv;
}

__global__ void k_apply3(const float* __restrict__ gmx, const float* __restrict__ gmn,
                         const float* __restrict__ m, const float* __restrict__ s,
                         const float* __restrict__ beta, float* __restrict__ out) {
    int i = blockIdx.x * blockDim.x + threadIdx.x;
    if (i >= Bb * 512) return;
    int b = i >> 9, o = i & 511;
    float mx = -1e30f, mn = 1e30f;
    for (int ch = 0; ch < 8; ++ch) {
        mx = fmaxf(mx, gmx[(size_t)(b * 8 + ch) * 512 + o]);
        mn = fminf(mn, gmn[(size_t)(b * 8 + ch) * 512 + o]);
    }
    float sc = s[o];
    float pick = (sc >= 0.f) ? mx : mn;
    out[i] = fmaxf((pick - m[o]) * sc + beta[o], 0.f);
}

static inline size_t align256(size_t x) { return (x + 255) & ~(size_t)255; }

extern "C" void kernel_launch(void* const* d_in, const int* in_sizes, int n_in,
                              void* d_out, int out_size, void* d_ws, size_t ws_size,
                              hipStream_t stream) {
    const float* pc  = (const float*)d_in[0];
    const float* w1a = (const float*)d_in[1];
    const float* g1a = (const float*)d_in[2];
    const float* b1a = (const float*)d_in[3];
    const float* w1b = (const float*)d_in[4];
    const float* g1b = (const float*)d_in[5];
    const float* b1b = (const float*)d_in[6];
    const float* w2a = (const float*)d_in[7];
    const float* g2a = (const float*)d_in[8];
    const float* b2a = (const float*)d_in[9];
    const float* w2b = (const float*)d_in[10];
    const float* g2b = (const float*)d_in[11];
    const float* b2b = (const float*)d_in[12];
    const float* w3  = (const float*)d_in[13];
    const float* g3  = (const float*)d_in[14];
    const float* b3  = (const float*)d_in[15];
    float* out = (float*)d_out;

    char* ws = (char*)d_ws;
    size_t off = 0;
    auto alloc = [&](size_t bytes) { void* p = ws + off; off += align256(bytes); return p; };

    float* xyz   = (float*)alloc(sizeof(float) * Bb * Nn * 3);
    float* xyz1  = (float*)alloc(sizeof(float) * Bb * S1 * 3);
    float* xyz2  = (float*)alloc(sizeof(float) * Bb * S2 * 3);
    int*   ni1   = (int*)alloc(sizeof(int) * Bb * S1 * K1);
    int*   ni2   = (int*)alloc(sizeof(int) * Bb * S2 * K2);
    float* gmx1  = (float*)alloc(sizeof(float) * (size_t)Bb * S1 * 128);  // also f1 after apply
    float* gmn1  = (float*)alloc(sizeof(float) * (size_t)Bb * S1 * 128);
    float* gmx2  = (float*)alloc(sizeof(float) * (size_t)Bb * S2 * 512);  // also f2 after apply
    float* gmn2  = (float*)alloc(sizeof(float) * (size_t)Bb * S2 * 512);
    float* gmx3  = (float*)alloc(sizeof(float) * 256 * 512);
    float* gmn3  = (float*)alloc(sizeof(float) * 256 * 512);
    double* dsum = (double*)alloc(sizeof(double) * 512);
    double* dsq  = (double*)alloc(sizeof(double) * 512);
    float* m1a = (float*)alloc(sizeof(float) * 64);
    float* s1a = (float*)alloc(sizeof(float) * 64);
    float* m1b = (float*)alloc(sizeof(float) * 128);
    float* s1b = (float*)alloc(sizeof(float) * 128);
    float* m2a = (float*)alloc(sizeof(float) * 128);
    float* s2a = (float*)alloc(sizeof(float) * 128);
    float* m2b = (float*)alloc(sizeof(float) * 512);
    float* s2b = (float*)alloc(sizeof(float) * 512);
    float* m3  = (float*)alloc(sizeof(float) * 512);
    float* s3  = (float*)alloc(sizeof(float) * 512);
    float* f1 = gmx1;  // in-place apply
    float* f2 = gmx2;
    // total ws ~ 40 MB

    // ---- Stage 1 ----
    k_transpose<<<(Bb * Nn + 255) / 256, 256, 0, stream>>>(pc, xyz);
    k_fps<<<Bb, 256, 0, stream>>>(xyz, Nn, S1, xyz1);
    k_ballquery<<<(Bb * S1 + 255) / 256, 256, 0, stream>>>(xyz, xyz1, Nn, S1, K1,
                                                           (float)(0.23 * 0.23), ni1);
    k_zero_stats<<<2, 256, 0, stream>>>(dsum, dsq, 512);
    k_s1_statsA<<<2048, 256, 0, stream>>>(xyz, xyz1, ni1, w1a, dsum, dsq);
    k_finalize<<<2, 256, 0, stream>>>(dsum, dsq, g1a, m1a, s1a, 64,
                                      1.0 / ((double)Bb * S1 * K1));
    k_zero_stats<<<2, 256, 0, stream>>>(dsum, dsq, 512);
    k_s1_main<<<1024, 256, 0, stream>>>(xyz, xyz1, ni1, w1a, m1a, s1a, b1a, w1b,
                                        dsum, dsq, gmx1, gmn1);
    k_finalize<<<2, 256, 0, stream>>>(dsum, dsq, g1b, m1b, s1b, 128,
                                      1.0 / ((double)Bb * S1 * K1));
    {
        long long tot = (long long)Bb * S1 * 128;
        k_applyMM<<<(int)((tot + 255) / 256), 256, 0, stream>>>(gmx1, gmn1, m1b, s1b, b1b,
                                                                f1, tot, 128);
    }
    // ---- Stage 2 ----
    k_fps<<<Bb, 256, 0, stream>>>(xyz1, S1, S2, xyz2);
    k_ballquery<<<(Bb * S2 + 255) / 256, 256, 0, stream>>>(xyz1, xyz2, S1, S2, K2,
                                                           (float)(0.32 * 0.32), ni2);
    k_zero_stats<<<2, 256, 0, stream>>>(dsum, dsq, 512);
    k_s2_statsA<<<1024, 256, 0, stream>>>(xyz1, xyz2, ni2, f1, w2a, dsum, dsq);
    k_finalize<<<2, 256, 0, stream>>>(dsum, dsq, g2a, m2a, s2a, 128,
                                      1.0 / ((double)Bb * S2 * K2));
    k_zero_stats<<<2, 256, 0, stream>>>(dsum, dsq, 512);
    k_s2_main<<<1024, 512, 0, stream>>>(xyz1, xyz2, ni2, f1, w2a, m2a, s2a, b2a, w2b,
                                        dsum, dsq, gmx2, gmn2);
    k_finalize<<<2, 256, 0, stream>>>(dsum, dsq, g2b, m2b, s2b, 512,
                                      1.0 / ((double)Bb * S2 * K2));
    {
        long long tot = (long long)Bb * S2 * 512;
        k_applyMM<<<(int)((tot + 255) / 256), 256, 0, stream>>>(gmx2, gmn2, m2b, s2b, b2b,
                                                                f2, tot, 512);
    }
    // ---- Stage 3 ----
    k_zero_stats<<<2, 256, 0, stream>>>(dsum, dsq, 512);
    k_s3<<<256, 512, 0, stream>>>(xyz2, f2, w3, dsum, dsq, gmx3, gmn3);
    k_finalize<<<2, 256, 0, stream>>>(dsum, dsq, g3, m3, s3, 512,
                                      1.0 / ((double)Bb * S2));
    k_apply3<<<(Bb * 512 + 255) / 256, 256, 0, stream>>>(gmx3, gmn3, m3, s3, b3, out);
}

// Round 4
// 3351.253 us; speedup vs baseline: 2.6971x; 1.0578x over previous
//
#include <hip/hip_runtime.h>
#include <math.h>

constexpr int Bb = 32, Nn = 2048;
constexpr int S1 = 512, K1 = 48;
constexpr int S2 = 128, K2 = 64;

#define DEVI __device__ __forceinline__

// Exact (non-FMA-contracted) squared distance, matches numpy ((dx^2+dy^2)+dz^2) fp32.
DEVI float sq3(float dx, float dy, float dz) {
    return __fadd_rn(__fadd_rn(__fmul_rn(dx, dx), __fmul_rn(dy, dy)), __fmul_rn(dz, dz));
}

// pc (B,3,N) -> xyz (B,N,3)
__global__ void k_transpose(const float* __restrict__ pc, float* __restrict__ xyz) {
    int i = blockIdx.x * blockDim.x + threadIdx.x;
    if (i >= Bb * Nn) return;
    int b = i / Nn;
    const float* s = pc + (size_t)b * 3 * Nn + (i % Nn);
    float* d = xyz + (size_t)i * 3;
    d[0] = s[0];
    d[1] = s[Nn];
    d[2] = s[2 * Nn];
}

// Farthest point sampling: one block per batch. Exact fp32; argmax first-occurrence.
__global__ void k_fps(const float* __restrict__ pts, int n, int npoint,
                      float* __restrict__ sel) {
    __shared__ float px[2048], py[2048], pz[2048], dist[2048];
    __shared__ float rv[256];
    __shared__ int ri[256];
    __shared__ int s_last;
    int b = blockIdx.x, tid = threadIdx.x;
    const float* base = pts + (size_t)b * n * 3;
    for (int j = tid; j < n; j += 256) {
        px[j] = base[j * 3 + 0];
        py[j] = base[j * 3 + 1];
        pz[j] = base[j * 3 + 2];
        dist[j] = 1e10f;
    }
    if (tid == 0) {
        s_last = 0;
        float* o = sel + (size_t)b * npoint * 3;
        o[0] = base[0]; o[1] = base[1]; o[2] = base[2];
    }
    __syncthreads();
    for (int i = 1; i < npoint; i++) {
        int last = s_last;
        float lx = px[last], ly = py[last], lz = pz[last];
        float bv = -1.0f;
        int bi = 0;
        for (int j = tid; j < n; j += 256) {
            float d = sq3(px[j] - lx, py[j] - ly, pz[j] - lz);
            float dd = fminf(dist[j], d);
            dist[j] = dd;
            if (dd > bv) { bv = dd; bi = j; }
        }
        rv[tid] = bv; ri[tid] = bi;
        __syncthreads();
        for (int off = 128; off > 0; off >>= 1) {
            if (tid < off) {
                float ov = rv[tid + off]; int oi = ri[tid + off];
                if (ov > rv[tid] || (ov == rv[tid] && oi < ri[tid])) { rv[tid] = ov; ri[tid] = oi; }
            }
            __syncthreads();
        }
        if (tid == 0) {
            int sp = ri[0];
            s_last = sp;
            float* o = sel + ((size_t)b * npoint + i) * 3;
            o[0] = px[sp]; o[1] = py[sp]; o[2] = pz[sp];
        }
        __syncthreads();
    }
}

// Ball query: thread per (b,center).
__global__ void k_ballquery(const float* __restrict__ src, const float* __restrict__ ctr,
                            int n, int m, int nsample, float r2, int* __restrict__ out) {
    int i = blockIdx.x * blockDim.x + threadIdx.x;
    if (i >= Bb * m) return;
    int b = i / m;
    const float* sb = src + (size_t)b * n * 3;
    float cx = ctr[(size_t)i * 3 + 0];
    float cy = ctr[(size_t)i * 3 + 1];
    float cz = ctr[(size_t)i * 3 + 2];
    int* ob = out + (size_t)i * nsample;
    int cnt = 0;
    for (int j = 0; j < n && cnt < nsample; j++) {
        float d2 = sq3(sb[j * 3 + 0] - cx, sb[j * 3 + 1] - cy, sb[j * 3 + 2] - cz);
        if (d2 < r2) ob[cnt++] = j;
    }
    int first = (cnt > 0) ? ob[0] : 0;
    for (int k = cnt; k < nsample; k++) ob[k] = first;
}

__global__ void k_zero_stats(double* dsum, double* dsq, int O) {
    int i = blockIdx.x * blockDim.x + threadIdx.x;
    if (i < O) { dsum[i] = 0.0; dsq[i] = 0.0; }
}

__global__ void k_finalize(const double* __restrict__ dsum, const double* __restrict__ dsq,
                           const float* __restrict__ g, float* __restrict__ mean,
                           float* __restrict__ scale, int O, double inv_count) {
    int o = blockIdx.x * blockDim.x + threadIdx.x;
    if (o < O) {
        double m = dsum[o] * inv_count;
        double v = dsq[o] * inv_count - m * m;
        mean[o] = (float)m;
        scale[o] = (float)((double)g[o] / sqrt(v + 1e-5));
    }
}

// Apply norm+relu to pooled minmax (in-place capable: f may alias gmx).
__global__ void k_applyMM(const float* __restrict__ gmx, const float* __restrict__ gmn,
                          const float* __restrict__ m, const float* __restrict__ s,
                          const float* __restrict__ beta, float* __restrict__ f,
                          long long total, int O) {
    long long i = (long long)blockIdx.x * blockDim.x + threadIdx.x;
    if (i >= total) return;
    int o = (int)(i % O);
    float sc = s[o];
    float pick = (sc >= 0.f) ? gmx[i] : gmn[i];
    f[i] = fmaxf((pick - m[o]) * sc + beta[o], 0.f);
}

// ---------------- Stage 1 ----------------
// Stats of y1a (C=6 -> O=64) over all (b,s,k).
__global__ __launch_bounds__(256)
void k_s1_statsA(const float* __restrict__ xyz, const float* __restrict__ xyz1,
                 const int* __restrict__ ni1, const float* __restrict__ w1a,
                 double* __restrict__ dsum, double* __restrict__ dsq) {
    __shared__ float red[256], red2[256];
    int t = threadIdx.x;
    float ls = 0.f, lsq = 0.f;
    for (int bs = blockIdx.x; bs < Bb * S1; bs += gridDim.x) {
        int b = bs >> 9;
        float cx = xyz1[bs * 3 + 0], cy = xyz1[bs * 3 + 1], cz = xyz1[bs * 3 + 2];
        for (int idx = t; idx < K1 * 64; idx += 256) {
            int k = idx >> 6, c = idx & 63;
            int j = ni1[bs * K1 + k];
            const float* g = xyz + ((size_t)b * Nn + j) * 3;
            float gx = g[0], gy = g[1], gz = g[2];
            const float* w = w1a + c * 6;
            float y = (gx - cx) * w[0] + (gy - cy) * w[1] + (gz - cz) * w[2]
                    + gx * w[3] + gy * w[4] + gz * w[5];
            ls += y; lsq += y * y;
        }
    }
    red[t] = ls; red2[t] = lsq;
    __syncthreads();
    if (t < 64) {
        double S = (double)red[t] + red[t + 64] + red[t + 128] + red[t + 192];
        double Q = (double)red2[t] + red2[t + 64] + red2[t + 128] + red2[t + 192];
        atomicAdd(&dsum[t], S); atomicAdd(&dsq[t], Q);
    }
}

// Main stage-1: x1 = relu(norm(y1a)); y1b (64->128): stats + per-(bs,o) max/min.
// Register tile 4o x 6k; x1 transposed [c][k] in LDS; w1bT [c][o] staged once.
constexpr int LDK1 = 50;  // 48 k + 2 pad (even, keeps b64 alignment)
__global__ __launch_bounds__(256)
void k_s1_main(const float* __restrict__ xyz, const float* __restrict__ xyz1,
               const int* __restrict__ ni1, const float* __restrict__ w1a,
               const float* __restrict__ m1a, const float* __restrict__ s1a,
               const float* __restrict__ beta1a, const float* __restrict__ w1b,
               double* __restrict__ dsum, double* __restrict__ dsq,
               float* __restrict__ gmx, float* __restrict__ gmn) {
    __shared__ float x1T[64 * LDK1];   // 12.8 KB  [c][k]
    __shared__ float wT[64 * 128];     // 32 KB    [c][o]
    int t = threadIdx.x;
    int og = t >> 3, kg = t & 7;       // 32 o-groups x 8 k-groups
    int o0 = og * 4, k0 = kg * 6;
    // stage w1bT once: read w1b[o][c] with lanes on consecutive o (uncoalesced but L2-hot),
    // write [c][o] conflict-free.
    for (int idx = t; idx < 64 * 128; idx += 256)
        wT[idx] = w1b[(size_t)(idx & 127) * 64 + (idx >> 7)];
    __syncthreads();
    float lsB[4] = {0.f, 0.f, 0.f, 0.f}, lqB[4] = {0.f, 0.f, 0.f, 0.f};
    for (int bs = blockIdx.x; bs < Bb * S1; bs += gridDim.x) {
        int b = bs >> 9;
        float cx = xyz1[bs * 3 + 0], cy = xyz1[bs * 3 + 1], cz = xyz1[bs * 3 + 2];
        // A: y1a -> x1T[c][k]
        #pragma unroll
        for (int i = 0; i < 12; ++i) {
            int idx = t + i * 256;
            int k = idx >> 6, c = idx & 63;
            int j = ni1[bs * K1 + k];
            const float* g = xyz + ((size_t)b * Nn + j) * 3;
            float gx = g[0], gy = g[1], gz = g[2];
            const float* w = w1a + c * 6;
            float y = (gx - cx) * w[0] + (gy - cy) * w[1] + (gz - cz) * w[2]
                    + gx * w[3] + gy * w[4] + gz * w[5];
            x1T[c * LDK1 + k] = fmaxf((y - m1a[c]) * s1a[c] + beta1a[c], 0.f);
        }
        __syncthreads();
        // B: y1b tile 4o x 6k
        float acc[24];
        #pragma unroll
        for (int i = 0; i < 24; ++i) acc[i] = 0.f;
        for (int c = 0; c < 64; ++c) {
            float4 wv = *(const float4*)&wT[c * 128 + o0];
            float2 xa = *(const float2*)&x1T[c * LDK1 + k0];
            float2 xb = *(const float2*)&x1T[c * LDK1 + k0 + 2];
            float2 xc = *(const float2*)&x1T[c * LDK1 + k0 + 4];
            float xs[6] = {xa.x, xa.y, xb.x, xb.y, xc.x, xc.y};
            float ws[4] = {wv.x, wv.y, wv.z, wv.w};
            #pragma unroll
            for (int i = 0; i < 4; ++i)
                #pragma unroll
                for (int j = 0; j < 6; ++j)
                    acc[i * 6 + j] = fmaf(ws[i], xs[j], acc[i * 6 + j]);
        }
        float mx[4], mn[4];
        #pragma unroll
        for (int i = 0; i < 4; ++i) {
            mx[i] = -1e30f; mn[i] = 1e30f;
            #pragma unroll
            for (int j = 0; j < 6; ++j) {
                float y = acc[i * 6 + j];
                lsB[i] += y; lqB[i] += y * y;
                mx[i] = fmaxf(mx[i], y); mn[i] = fminf(mn[i], y);
            }
        }
        #pragma unroll
        for (int off = 4; off > 0; off >>= 1)
            #pragma unroll
            for (int i = 0; i < 4; ++i) {
                mx[i] = fmaxf(mx[i], __shfl_down(mx[i], off));
                mn[i] = fminf(mn[i], __shfl_down(mn[i], off));
            }
        if (kg == 0) {
            *(float4*)&gmx[(size_t)bs * 128 + o0] = make_float4(mx[0], mx[1], mx[2], mx[3]);
            *(float4*)&gmn[(size_t)bs * 128 + o0] = make_float4(mn[0], mn[1], mn[2], mn[3]);
        }
        __syncthreads();
    }
    #pragma unroll
    for (int off = 4; off > 0; off >>= 1)
        #pragma unroll
        for (int i = 0; i < 4; ++i) {
            lsB[i] += __shfl_down(lsB[i], off);
            lqB[i] += __shfl_down(lqB[i], off);
        }
    if (kg == 0)
        #pragma unroll
        for (int i = 0; i < 4; ++i) {
            atomicAdd(&dsum[o0 + i], (double)lsB[i]);
            atomicAdd(&dsq[o0 + i], (double)lqB[i]);
        }
}

// ---------------- Stage 2 ----------------
constexpr int LDK2 = 68;  // 64 k + 4 pad (keeps b128 alignment of rows)

// Gather tile in transposed layout xT[c][k] (c=0..133).
DEVI void s2_gatherT(int t, int bs, const float* xyz1, const float* xyz2,
                     const int* ni2, const float* f1, float* xT) {
    int b = bs >> 7;
    float cx = xyz2[bs * 3 + 0], cy = xyz2[bs * 3 + 1], cz = xyz2[bs * 3 + 2];
    for (int idx = t; idx < K2 * 134; idx += 512) {
        int k = idx / 134, c = idx - k * 134;
        int j = ni2[bs * K2 + k];
        const float* p1 = xyz1 + ((size_t)b * S1 + j) * 3;
        float v;
        if (c < 3)      v = p1[c] - (c == 0 ? cx : (c == 1 ? cy : cz));
        else if (c < 6) v = p1[c - 3];
        else            v = f1[((size_t)b * S1 + j) * 128 + (c - 6)];
        xT[c * LDK2 + k] = v;
    }
}

// Stats of y2a (C=134 -> O=128). Tile 4o x 4k; full w2aT staged once.
__global__ __launch_bounds__(512)
void k_s2_statsA(const float* __restrict__ xyz1, const float* __restrict__ xyz2,
                 const int* __restrict__ ni2, const float* __restrict__ f1,
                 const float* __restrict__ w2a,
                 double* __restrict__ dsum, double* __restrict__ dsq) {
    __shared__ float xT[134 * LDK2];   // 36.4 KB
    __shared__ float wT[134 * 128];    // 68.6 KB
    int t = threadIdx.x;
    int og = t >> 4, kg = t & 15;      // 32 x 16
    int o0 = og * 4, k0 = kg * 4;
    for (int idx = t; idx < 134 * 128; idx += 512)
        wT[idx] = w2a[(size_t)(idx & 127) * 134 + (idx >> 7)];
    float ls[4] = {0.f, 0.f, 0.f, 0.f}, lq[4] = {0.f, 0.f, 0.f, 0.f};
    for (int bs = blockIdx.x; bs < Bb * S2; bs += gridDim.x) {
        __syncthreads();
        s2_gatherT(t, bs, xyz1, xyz2, ni2, f1, xT);
        __syncthreads();
        float acc[16];
        #pragma unroll
        for (int i = 0; i < 16; ++i) acc[i] = 0.f;
        for (int c = 0; c < 134; ++c) {
            float4 wv = *(const float4*)&wT[c * 128 + o0];
            float4 xv = *(const float4*)&xT[c * LDK2 + k0];
            float ws[4] = {wv.x, wv.y, wv.z, wv.w};
            float xs[4] = {xv.x, xv.y, xv.z, xv.w};
            #pragma unroll
            for (int i = 0; i < 4; ++i)
                #pragma unroll
                for (int j = 0; j < 4; ++j)
                    acc[i * 4 + j] = fmaf(ws[i], xs[j], acc[i * 4 + j]);
        }
        #pragma unroll
        for (int i = 0; i < 4; ++i)
            #pragma unroll
            for (int j = 0; j < 4; ++j) {
                float y = acc[i * 4 + j];
                ls[i] += y; lq[i] += y * y;
            }
    }
    #pragma unroll
    for (int off = 8; off > 0; off >>= 1)
        #pragma unroll
        for (int i = 0; i < 4; ++i) {
            ls[i] += __shfl_down(ls[i], off);
            lq[i] += __shfl_down(lq[i], off);
        }
    if (kg == 0)
        #pragma unroll
        for (int i = 0; i < 4; ++i) {
            atomicAdd(&dsum[o0 + i], (double)ls[i]);
            atomicAdd(&dsq[o0 + i], (double)lq[i]);
        }
}

// Main stage-2: A: y2a -> x2 (4o x 4k regs) -> x2T in LDS (overwrites gather tile);
// B: y2b (128->512) tile 4o x 16k, w2b staged in 16-c chunks; stats + minmax.
__global__ __launch_bounds__(512)
void k_s2_main(const float* __restrict__ xyz1, const float* __restrict__ xyz2,
               const int* __restrict__ ni2, const float* __restrict__ f1,
               const float* __restrict__ w2a,
               const float* __restrict__ m2a, const float* __restrict__ s2a,
               const float* __restrict__ beta2a, const float* __restrict__ w2b,
               double* __restrict__ dsum, double* __restrict__ dsq,
               float* __restrict__ gmx, float* __restrict__ gmn) {
    __shared__ float xT[134 * LDK2];   // 36.4 KB; rows 0..127 reused as x2T[c2][k]
    __shared__ float waT[134 * 128];   // 68.6 KB
    __shared__ float wbT[16 * 512];    // 32 KB, chunk [cc][o]
    int t = threadIdx.x;
    int ogA = t >> 4, kgA = t & 15;    // A: 32 x 16 -> 4o x 4k
    int o0A = ogA * 4, k0A = kgA * 4;
    int ogB = t >> 2, kgB = t & 3;     // B: 128 x 4 -> 4o x 16k
    int o0B = ogB * 4, k0B = kgB * 16;
    for (int idx = t; idx < 134 * 128; idx += 512)
        waT[idx] = w2a[(size_t)(idx & 127) * 134 + (idx >> 7)];
    float lsB[4] = {0.f, 0.f, 0.f, 0.f}, lqB[4] = {0.f, 0.f, 0.f, 0.f};
    for (int bs = blockIdx.x; bs < Bb * S2; bs += gridDim.x) {
        __syncthreads();
        s2_gatherT(t, bs, xyz1, xyz2, ni2, f1, xT);
        __syncthreads();
        // A: y2a tile
        float acc[16];
        #pragma unroll
        for (int i = 0; i < 16; ++i) acc[i] = 0.f;
        for (int c = 0; c < 134; ++c) {
            float4 wv = *(const float4*)&waT[c * 128 + o0A];
            float4 xv = *(const float4*)&xT[c * LDK2 + k0A];
            float ws[4] = {wv.x, wv.y, wv.z, wv.w};
            float xs[4] = {xv.x, xv.y, xv.z, xv.w};
            #pragma unroll
            for (int i = 0; i < 4; ++i)
                #pragma unroll
                for (int j = 0; j < 4; ++j)
                    acc[i * 4 + j] = fmaf(ws[i], xs[j], acc[i * 4 + j]);
        }
        float4 mam = *(const float4*)&m2a[o0A];
        float4 sam = *(const float4*)&s2a[o0A];
        float4 bam = *(const float4*)&beta2a[o0A];
        float ma[4] = {mam.x, mam.y, mam.z, mam.w};
        float sa[4] = {sam.x, sam.y, sam.z, sam.w};
        float ba[4] = {bam.x, bam.y, bam.z, bam.w};
        __syncthreads();  // all xT reads done before overwrite
        #pragma unroll
        for (int i = 0; i < 4; ++i) {
            float4 v;
            v.x = fmaxf((acc[i * 4 + 0] - ma[i]) * sa[i] + ba[i], 0.f);
            v.y = fmaxf((acc[i * 4 + 1] - ma[i]) * sa[i] + ba[i], 0.f);
            v.z = fmaxf((acc[i * 4 + 2] - ma[i]) * sa[i] + ba[i], 0.f);
            v.w = fmaxf((acc[i * 4 + 3] - ma[i]) * sa[i] + ba[i], 0.f);
            *(float4*)&xT[(o0A + i) * LDK2 + k0A] = v;  // x2T[c2][k]
        }
        __syncthreads();
        // B: y2b tile 4o x 16k, c chunked by 16
        float accB[64];
        #pragma unroll
        for (int i = 0; i < 64; ++i) accB[i] = 0.f;
        for (int cb = 0; cb < 128; cb += 16) {
            #pragma unroll
            for (int i2 = 0; i2 < 16; ++i2) {
                int idx = t + i2 * 512;
                int cc = idx & 15, o = idx >> 4;
                wbT[cc * 512 + o] = w2b[(size_t)o * 128 + cb + cc];
            }
            __syncthreads();
            for (int cc = 0; cc < 16; ++cc) {
                float4 wv = *(const float4*)&wbT[cc * 512 + o0B];
                const float* xr = &xT[(cb + cc) * LDK2 + k0B];
                float4 x0 = *(const float4*)(xr);
                float4 x1 = *(const float4*)(xr + 4);
                float4 x2 = *(const float4*)(xr + 8);
                float4 x3 = *(const float4*)(xr + 12);
                float ws[4] = {wv.x, wv.y, wv.z, wv.w};
                float xs[16] = {x0.x, x0.y, x0.z, x0.w, x1.x, x1.y, x1.z, x1.w,
                                x2.x, x2.y, x2.z, x2.w, x3.x, x3.y, x3.z, x3.w};
                #pragma unroll
                for (int i = 0; i < 4; ++i)
                    #pragma unroll
                    for (int j = 0; j < 16; ++j)
                        accB[i * 16 + j] = fmaf(ws[i], xs[j], accB[i * 16 + j]);
            }
            __syncthreads();
        }
        float mxB[4], mnB[4];
        #pragma unroll
        for (int i = 0; i < 4; ++i) {
            mxB[i] = -1e30f; mnB[i] = 1e30f;
            #pragma unroll
            for (int j = 0; j < 16; ++j) {
                float y = accB[i * 16 + j];
                lsB[i] += y; lqB[i] += y * y;
                mxB[i] = fmaxf(mxB[i], y); mnB[i] = fminf(mnB[i], y);
            }
        }
        #pragma unroll
        for (int off = 2; off > 0; off >>= 1)
            #pragma unroll
            for (int i = 0; i < 4; ++i) {
                mxB[i] = fmaxf(mxB[i], __shfl_down(mxB[i], off));
                mnB[i] = fminf(mnB[i], __shfl_down(mnB[i], off));
            }
        if (kgB == 0) {
            *(float4*)&gmx[(size_t)bs * 512 + o0B] = make_float4(mxB[0], mxB[1], mxB[2], mxB[3]);
            *(float4*)&gmn[(size_t)bs * 512 + o0B] = make_float4(mnB[0], mnB[1], mnB[2], mnB[3]);
        }
    }
    #pragma unroll
    for (int off = 2; off > 0; off >>= 1)
        #pragma unroll
        for (int i = 0; i < 4; ++i) {
            lsB[i] += __shfl_down(lsB[i], off);
            lqB[i] += __shfl_down(lqB[i], off);
        }
    if (kgB == 0)
        #pragma unroll
        for (int i = 0; i < 4; ++i) {
            atomicAdd(&dsum[o0B + i], (double)lsB[i]);
            atomicAdd(&dsq[o0B + i], (double)lqB[i]);
        }
}

// ---------------- Stage 3 ----------------
constexpr int X3_LD = 520;  // 515 real + 5 zero pad

__global__ __launch_bounds__(512)
void k_s3(const float* __restrict__ xyz2, const float* __restrict__ f2,
          const float* __restrict__ w3, double* __restrict__ dsum,
          double* __restrict__ dsq, float* __restrict__ gmx, float* __restrict__ gmn) {
    __shared__ float xt[16 * X3_LD];  // 33.3 KB
    int b = blockIdx.x >> 3, kc = blockIdx.x & 7;
    int t = threadIdx.x;  // = o
    for (int idx = t; idx < 16 * X3_LD; idx += 512) {
        int rr = idx / X3_LD, c = idx - rr * X3_LD;
        int row = b * S2 + kc * 16 + rr;
        float v;
        if (c < 3)        v = xyz2[row * 3 + c];
        else if (c < 515) v = f2[(size_t)row * 512 + (c - 3)];
        else              v = 0.f;
        xt[idx] = v;
    }
    __syncthreads();
    float acc[16];
    #pragma unroll
    for (int rr = 0; rr < 16; ++rr) acc[rr] = 0.f;
    for (int ct = 0; ct < 16; ++ct) {
        float wr[32];
        #pragma unroll
        for (int i = 0; i < 32; ++i) wr[i] = w3[(size_t)t * 515 + ct * 32 + i];
        #pragma unroll
        for (int rr = 0; rr < 16; ++rr) {
            const float* xr = &xt[rr * X3_LD + ct * 32];
            #pragma unroll
            for (int j = 0; j < 8; ++j) {
                float4 x = *(const float4*)(xr + 4 * j);
                acc[rr] = fmaf(x.x, wr[4 * j + 0], acc[rr]);
                acc[rr] = fmaf(x.y, wr[4 * j + 1], acc[rr]);
                acc[rr] = fmaf(x.z, wr[4 * j + 2], acc[rr]);
                acc[rr] = fmaf(x.w, wr[4 * j + 3], acc[rr]);
            }
        }
    }
    {
        float wr[8];
        #pragma unroll
        for (int i = 0; i < 8; ++i) wr[i] = (i < 3) ? w3[(size_t)t * 515 + 512 + i] : 0.f;
        #pragma unroll
        for (int rr = 0; rr < 16; ++rr) {
            const float* xr = &xt[rr * X3_LD + 512];
            #pragma unroll
            for (int j = 0; j < 2; ++j) {
                float4 x = *(const float4*)(xr + 4 * j);
                acc[rr] = fmaf(x.x, wr[4 * j + 0], acc[rr]);
                acc[rr] = fmaf(x.y, wr[4 * j + 1], acc[rr]);
                acc[rr] = fmaf(x.z, wr[4 * j + 2], acc[rr]);
                acc[rr] = fmaf(x.w, wr[4 * j + 3], acc[rr]);
            }
        }
    }
    float ls = 0.f, lsq = 0.f, mxv = -1e30f, mnv = 1e30f;
    #pragma unroll
    for (int rr = 0; rr < 16; ++rr) {
        float y = acc[rr];
        ls += y; lsq += y * y;
        mxv = fmaxf(mxv, y); mnv = fminf(mnv, y);
    }
    atomicAdd(&dsum[t], (double)ls);
    atomicAdd(&dsq[t], (double)lsq);
    gmx[(size_t)blockIdx.x * 512 + t] = mxv;
    gmn[(size_t)blockIdx.x * 512 + t] = mnv;
}

__global__ void k_apply3(const float* __restrict__ gmx, const float* __restrict__ gmn,
                         const float* __restrict__ m, const float* __restrict__ s,
                         const float* __restrict__ beta, float* __restrict__ out) {
    int i = blockIdx.x * blockDim.x + threadIdx.x;
    if (i >= Bb * 512) return;
    int b = i >> 9, o = i & 511;
    float mx = -1e30f, mn = 1e30f;
    for (int ch = 0; ch < 8; ++ch) {
        mx = fmaxf(mx, gmx[(size_t)(b * 8 + ch) * 512 + o]);
        mn = fminf(mn, gmn[(size_t)(b * 8 + ch) * 512 + o]);
    }
    float sc = s[o];
    float pick = (sc >= 0.f) ? mx : mn;
    out[i] = fmaxf((pick - m[o]) * sc + beta[o], 0.f);
}

static inline size_t align256(size_t x) { return (x + 255) & ~(size_t)255; }

extern "C" void kernel_launch(void* const* d_in, const int* in_sizes, int n_in,
                              void* d_out, int out_size, void* d_ws, size_t ws_size,
                              hipStream_t stream) {
    const float* pc  = (const float*)d_in[0];
    const float* w1a = (const float*)d_in[1];
    const float* g1a = (const float*)d_in[2];
    const float* b1a = (const float*)d_in[3];
    const float* w1b = (const float*)d_in[4];
    const float* g1b = (const float*)d_in[5];
    const float* b1b = (const float*)d_in[6];
    const float* w2a = (const float*)d_in[7];
    const float* g2a = (const float*)d_in[8];
    const float* b2a = (const float*)d_in[9];
    const float* w2b = (const float*)d_in[10];
    const float* g2b = (const float*)d_in[11];
    const float* b2b = (const float*)d_in[12];
    const float* w3  = (const float*)d_in[13];
    const float* g3  = (const float*)d_in[14];
    const float* b3  = (const float*)d_in[15];
    float* out = (float*)d_out;

    char* ws = (char*)d_ws;
    size_t off = 0;
    auto alloc = [&](size_t bytes) { void* p = ws + off; off += align256(bytes); return p; };

    float* xyz   = (float*)alloc(sizeof(float) * Bb * Nn * 3);
    float* xyz1  = (float*)alloc(sizeof(float) * Bb * S1 * 3);
    float* xyz2  = (float*)alloc(sizeof(float) * Bb * S2 * 3);
    int*   ni1   = (int*)alloc(sizeof(int) * Bb * S1 * K1);
    int*   ni2   = (int*)alloc(sizeof(int) * Bb * S2 * K2);
    float* gmx1  = (float*)alloc(sizeof(float) * (size_t)Bb * S1 * 128);  // f1 after apply
    float* gmn1  = (float*)alloc(sizeof(float) * (size_t)Bb * S1 * 128);
    float* gmx2  = (float*)alloc(sizeof(float) * (size_t)Bb * S2 * 512);  // f2 after apply
    float* gmn2  = (float*)alloc(sizeof(float) * (size_t)Bb * S2 * 512);
    float* gmx3  = (float*)alloc(sizeof(float) * 256 * 512);
    float* gmn3  = (float*)alloc(sizeof(float) * 256 * 512);
    double* dsum = (double*)alloc(sizeof(double) * 512);
    double* dsq  = (double*)alloc(sizeof(double) * 512);
    float* m1a = (float*)alloc(sizeof(float) * 64);
    float* s1a = (float*)alloc(sizeof(float) * 64);
    float* m1b = (float*)alloc(sizeof(float) * 128);
    float* s1b = (float*)alloc(sizeof(float) * 128);
    float* m2a = (float*)alloc(sizeof(float) * 128);
    float* s2a = (float*)alloc(sizeof(float) * 128);
    float* m2b = (float*)alloc(sizeof(float) * 512);
    float* s2b = (float*)alloc(sizeof(float) * 512);
    float* m3  = (float*)alloc(sizeof(float) * 512);
    float* s3  = (float*)alloc(sizeof(float) * 512);
    float* f1 = gmx1;  // in-place apply
    float* f2 = gmx2;

    // ---- Stage 1 ----
    k_transpose<<<(Bb * Nn + 255) / 256, 256, 0, stream>>>(pc, xyz);
    k_fps<<<Bb, 256, 0, stream>>>(xyz, Nn, S1, xyz1);
    k_ballquery<<<(Bb * S1 + 255) / 256, 256, 0, stream>>>(xyz, xyz1, Nn, S1, K1,
                                                           (float)(0.23 * 0.23), ni1);
    k_zero_stats<<<2, 256, 0, stream>>>(dsum, dsq, 512);
    k_s1_statsA<<<2048, 256, 0, stream>>>(xyz, xyz1, ni1, w1a, dsum, dsq);
    k_finalize<<<2, 256, 0, stream>>>(dsum, dsq, g1a, m1a, s1a, 64,
                                      1.0 / ((double)Bb * S1 * K1));
    k_zero_stats<<<2, 256, 0, stream>>>(dsum, dsq, 512);
    k_s1_main<<<1024, 256, 0, stream>>>(xyz, xyz1, ni1, w1a, m1a, s1a, b1a, w1b,
                                        dsum, dsq, gmx1, gmn1);
    k_finalize<<<2, 256, 0, stream>>>(dsum, dsq, g1b, m1b, s1b, 128,
                                      1.0 / ((double)Bb * S1 * K1));
    {
        long long tot = (long long)Bb * S1 * 128;
        k_applyMM<<<(int)((tot + 255) / 256), 256, 0, stream>>>(gmx1, gmn1, m1b, s1b, b1b,
                                                                f1, tot, 128);
    }
    // ---- Stage 2 ----
    k_fps<<<Bb, 256, 0, stream>>>(xyz1, S1, S2, xyz2);
    k_ballquery<<<(Bb * S2 + 255) / 256, 256, 0, stream>>>(xyz1, xyz2, S1, S2, K2,
                                                           (float)(0.32 * 0.32), ni2);
    k_zero_stats<<<2, 256, 0, stream>>>(dsum, dsq, 512);
    k_s2_statsA<<<1024, 512, 0, stream>>>(xyz1, xyz2, ni2, f1, w2a, dsum, dsq);
    k_finalize<<<2, 256, 0, stream>>>(dsum, dsq, g2a, m2a, s2a, 128,
                                      1.0 / ((double)Bb * S2 * K2));
    k_zero_stats<<<2, 256, 0, stream>>>(dsum, dsq, 512);
    k_s2_main<<<1024, 512, 0, stream>>>(xyz1, xyz2, ni2, f1, w2a, m2a, s2a, b2a, w2b,
                                        dsum, dsq, gmx2, gmn2);
    k_finalize<<<2, 256, 0, stream>>>(dsum, dsq, g2b, m2b, s2b, 512,
                                      1.0 / ((double)Bb * S2 * K2));
    {
        long long tot = (long long)Bb * S2 * 512;
        k_applyMM<<<(int)((tot + 255) / 256), 256, 0, stream>>>(gmx2, gmn2, m2b, s2b, b2b,
                                                                f2, tot, 512);
    }
    // ---- Stage 3 ----
    k_zero_stats<<<2, 256, 0, stream>>>(dsum, dsq, 512);
    k_s3<<<256, 512, 0, stream>>>(xyz2, f2, w3, dsum, dsq, gmx3, gmn3);
    k_finalize<<<2, 256, 0, stream>>>(dsum, dsq, g3, m3, s3, 512,
                                      1.0 / ((double)Bb * S2));
    k_apply3<<<(Bb * 512 + 255) / 256, 256, 0, stream>>>(gmx3, gmn3, m3, s3, b3, out);
}

// Round 5
// 2847.643 us; speedup vs baseline: 3.1741x; 1.1769x over previous
//
#include <hip/hip_runtime.h>
#include <math.h>

constexpr int Bb = 32, Nn = 2048;
constexpr int S1 = 512, K1 = 48;
constexpr int S2 = 128, K2 = 64;

#define DEVI __device__ __forceinline__

// Exact (non-FMA-contracted) squared distance, matches numpy ((dx^2+dy^2)+dz^2) fp32.
DEVI float sq3(float dx, float dy, float dz) {
    return __fadd_rn(__fadd_rn(__fmul_rn(dx, dx), __fmul_rn(dy, dy)), __fmul_rn(dz, dz));
}

// pc (B,3,N) -> xyz (B,N,3)
__global__ void k_transpose(const float* __restrict__ pc, float* __restrict__ xyz) {
    int i = blockIdx.x * blockDim.x + threadIdx.x;
    if (i >= Bb * Nn) return;
    int b = i / Nn;
    const float* s = pc + (size_t)b * 3 * Nn + (i % Nn);
    float* d = xyz + (size_t)i * 3;
    d[0] = s[0];
    d[1] = s[Nn];
    d[2] = s[2 * Nn];
}

// Transpose stage-2 weights into [c][o] layout (one-time, tiny).
__global__ void k_wtrans(const float* __restrict__ w2a, const float* __restrict__ w2b,
                         float* __restrict__ w2aT, float* __restrict__ w2bT) {
    int i = blockIdx.x * blockDim.x + threadIdx.x;
    if (i < 134 * 128) {
        int c = i >> 7, o = i & 127;
        w2aT[i] = w2a[(size_t)o * 134 + c];
    }
    if (i < 128 * 512) {
        int c = i >> 9, o = i & 511;
        w2bT[i] = w2b[(size_t)o * 128 + c];
    }
}

// Farthest point sampling: one block per batch. Exact fp32; argmax first-occurrence.
__global__ void k_fps(const float* __restrict__ pts, int n, int npoint,
                      float* __restrict__ sel) {
    __shared__ float px[2048], py[2048], pz[2048], dist[2048];
    __shared__ float rv[256];
    __shared__ int ri[256];
    __shared__ int s_last;
    int b = blockIdx.x, tid = threadIdx.x;
    const float* base = pts + (size_t)b * n * 3;
    for (int j = tid; j < n; j += 256) {
        px[j] = base[j * 3 + 0];
        py[j] = base[j * 3 + 1];
        pz[j] = base[j * 3 + 2];
        dist[j] = 1e10f;
    }
    if (tid == 0) {
        s_last = 0;
        float* o = sel + (size_t)b * npoint * 3;
        o[0] = base[0]; o[1] = base[1]; o[2] = base[2];
    }
    __syncthreads();
    for (int i = 1; i < npoint; i++) {
        int last = s_last;
        float lx = px[last], ly = py[last], lz = pz[last];
        float bv = -1.0f;
        int bi = 0;
        for (int j = tid; j < n; j += 256) {
            float d = sq3(px[j] - lx, py[j] - ly, pz[j] - lz);
            float dd = fminf(dist[j], d);
            dist[j] = dd;
            if (dd > bv) { bv = dd; bi = j; }
        }
        rv[tid] = bv; ri[tid] = bi;
        __syncthreads();
        for (int off = 128; off > 0; off >>= 1) {
            if (tid < off) {
                float ov = rv[tid + off]; int oi = ri[tid + off];
                if (ov > rv[tid] || (ov == rv[tid] && oi < ri[tid])) { rv[tid] = ov; ri[tid] = oi; }
            }
            __syncthreads();
        }
        if (tid == 0) {
            int sp = ri[0];
            s_last = sp;
            float* o = sel + ((size_t)b * npoint + i) * 3;
            o[0] = px[sp]; o[1] = py[sp]; o[2] = pz[sp];
        }
        __syncthreads();
    }
}

// Ball query: thread per (b,center).
__global__ void k_ballquery(const float* __restrict__ src, const float* __restrict__ ctr,
                            int n, int m, int nsample, float r2, int* __restrict__ out) {
    int i = blockIdx.x * blockDim.x + threadIdx.x;
    if (i >= Bb * m) return;
    int b = i / m;
    const float* sb = src + (size_t)b * n * 3;
    float cx = ctr[(size_t)i * 3 + 0];
    float cy = ctr[(size_t)i * 3 + 1];
    float cz = ctr[(size_t)i * 3 + 2];
    int* ob = out + (size_t)i * nsample;
    int cnt = 0;
    for (int j = 0; j < n && cnt < nsample; j++) {
        float d2 = sq3(sb[j * 3 + 0] - cx, sb[j * 3 + 1] - cy, sb[j * 3 + 2] - cz);
        if (d2 < r2) ob[cnt++] = j;
    }
    int first = (cnt > 0) ? ob[0] : 0;
    for (int k = cnt; k < nsample; k++) ob[k] = first;
}

__global__ void k_zero_stats(double* dsum, double* dsq, int O) {
    int i = blockIdx.x * blockDim.x + threadIdx.x;
    if (i < O) { dsum[i] = 0.0; dsq[i] = 0.0; }
}

__global__ void k_finalize(const double* __restrict__ dsum, const double* __restrict__ dsq,
                           const float* __restrict__ g, float* __restrict__ mean,
                           float* __restrict__ scale, int O, double inv_count) {
    int o = blockIdx.x * blockDim.x + threadIdx.x;
    if (o < O) {
        double m = dsum[o] * inv_count;
        double v = dsq[o] * inv_count - m * m;
        mean[o] = (float)m;
        scale[o] = (float)((double)g[o] / sqrt(v + 1e-5));
    }
}

// Apply norm+relu to pooled minmax (in-place capable: f may alias gmx).
__global__ void k_applyMM(const float* __restrict__ gmx, const float* __restrict__ gmn,
                          const float* __restrict__ m, const float* __restrict__ s,
                          const float* __restrict__ beta, float* __restrict__ f,
                          long long total, int O) {
    long long i = (long long)blockIdx.x * blockDim.x + threadIdx.x;
    if (i >= total) return;
    int o = (int)(i % O);
    float sc = s[o];
    float pick = (sc >= 0.f) ? gmx[i] : gmn[i];
    f[i] = fmaxf((pick - m[o]) * sc + beta[o], 0.f);
}

// ---------------- Stage 1 ----------------
// Stats of y1a (C=6 -> O=64) over all (b,s,k).
__global__ __launch_bounds__(256)
void k_s1_statsA(const float* __restrict__ xyz, const float* __restrict__ xyz1,
                 const int* __restrict__ ni1, const float* __restrict__ w1a,
                 double* __restrict__ dsum, double* __restrict__ dsq) {
    __shared__ float red[256], red2[256];
    int t = threadIdx.x;
    float ls = 0.f, lsq = 0.f;
    for (int bs = blockIdx.x; bs < Bb * S1; bs += gridDim.x) {
        int b = bs >> 9;
        float cx = xyz1[bs * 3 + 0], cy = xyz1[bs * 3 + 1], cz = xyz1[bs * 3 + 2];
        for (int idx = t; idx < K1 * 64; idx += 256) {
            int k = idx >> 6, c = idx & 63;
            int j = ni1[bs * K1 + k];
            const float* g = xyz + ((size_t)b * Nn + j) * 3;
            float gx = g[0], gy = g[1], gz = g[2];
            const float* w = w1a + c * 6;
            float y = (gx - cx) * w[0] + (gy - cy) * w[1] + (gz - cz) * w[2]
                    + gx * w[3] + gy * w[4] + gz * w[5];
            ls += y; lsq += y * y;
        }
    }
    red[t] = ls; red2[t] = lsq;
    __syncthreads();
    if (t < 64) {
        double S = (double)red[t] + red[t + 64] + red[t + 128] + red[t + 192];
        double Q = (double)red2[t] + red2[t + 64] + red2[t + 128] + red2[t + 192];
        atomicAdd(&dsum[t], S); atomicAdd(&dsq[t], Q);
    }
}

// Main stage-1: x1 = relu(norm(y1a)); y1b (64->128): stats + per-(bs,o) max/min.
// Register tile 4o x 6k; x1 transposed [c][k] in LDS; w1bT [c][o] staged once.
constexpr int LDK1 = 50;  // 48 k + 2 pad (even, keeps b64 alignment)
__global__ __launch_bounds__(256)
void k_s1_main(const float* __restrict__ xyz, const float* __restrict__ xyz1,
               const int* __restrict__ ni1, const float* __restrict__ w1a,
               const float* __restrict__ m1a, const float* __restrict__ s1a,
               const float* __restrict__ beta1a, const float* __restrict__ w1b,
               double* __restrict__ dsum, double* __restrict__ dsq,
               float* __restrict__ gmx, float* __restrict__ gmn) {
    __shared__ float x1T[64 * LDK1];   // 12.8 KB  [c][k]
    __shared__ float wT[64 * 128];     // 32 KB    [c][o]
    int t = threadIdx.x;
    int og = t >> 3, kg = t & 7;       // 32 o-groups x 8 k-groups
    int o0 = og * 4, k0 = kg * 6;
    for (int idx = t; idx < 64 * 128; idx += 256)
        wT[idx] = w1b[(size_t)(idx & 127) * 64 + (idx >> 7)];
    __syncthreads();
    float lsB[4] = {0.f, 0.f, 0.f, 0.f}, lqB[4] = {0.f, 0.f, 0.f, 0.f};
    for (int bs = blockIdx.x; bs < Bb * S1; bs += gridDim.x) {
        int b = bs >> 9;
        float cx = xyz1[bs * 3 + 0], cy = xyz1[bs * 3 + 1], cz = xyz1[bs * 3 + 2];
        // A: y1a -> x1T[c][k]
        #pragma unroll
        for (int i = 0; i < 12; ++i) {
            int idx = t + i * 256;
            int k = idx >> 6, c = idx & 63;
            int j = ni1[bs * K1 + k];
            const float* g = xyz + ((size_t)b * Nn + j) * 3;
            float gx = g[0], gy = g[1], gz = g[2];
            const float* w = w1a + c * 6;
            float y = (gx - cx) * w[0] + (gy - cy) * w[1] + (gz - cz) * w[2]
                    + gx * w[3] + gy * w[4] + gz * w[5];
            x1T[c * LDK1 + k] = fmaxf((y - m1a[c]) * s1a[c] + beta1a[c], 0.f);
        }
        __syncthreads();
        // B: y1b tile 4o x 6k
        float acc[24];
        #pragma unroll
        for (int i = 0; i < 24; ++i) acc[i] = 0.f;
        for (int c = 0; c < 64; ++c) {
            float4 wv = *(const float4*)&wT[c * 128 + o0];
            float2 xa = *(const float2*)&x1T[c * LDK1 + k0];
            float2 xb = *(const float2*)&x1T[c * LDK1 + k0 + 2];
            float2 xc = *(const float2*)&x1T[c * LDK1 + k0 + 4];
            float xs[6] = {xa.x, xa.y, xb.x, xb.y, xc.x, xc.y};
            float ws[4] = {wv.x, wv.y, wv.z, wv.w};
            #pragma unroll
            for (int i = 0; i < 4; ++i)
                #pragma unroll
                for (int j = 0; j < 6; ++j)
                    acc[i * 6 + j] = fmaf(ws[i], xs[j], acc[i * 6 + j]);
        }
        float mx[4], mn[4];
        #pragma unroll
        for (int i = 0; i < 4; ++i) {
            mx[i] = -1e30f; mn[i] = 1e30f;
            #pragma unroll
            for (int j = 0; j < 6; ++j) {
                float y = acc[i * 6 + j];
                lsB[i] += y; lqB[i] += y * y;
                mx[i] = fmaxf(mx[i], y); mn[i] = fminf(mn[i], y);
            }
        }
        #pragma unroll
        for (int off = 4; off > 0; off >>= 1)
            #pragma unroll
            for (int i = 0; i < 4; ++i) {
                mx[i] = fmaxf(mx[i], __shfl_down(mx[i], off));
                mn[i] = fminf(mn[i], __shfl_down(mn[i], off));
            }
        if (kg == 0) {
            *(float4*)&gmx[(size_t)bs * 128 + o0] = make_float4(mx[0], mx[1], mx[2], mx[3]);
            *(float4*)&gmn[(size_t)bs * 128 + o0] = make_float4(mn[0], mn[1], mn[2], mn[3]);
        }
        __syncthreads();
    }
    #pragma unroll
    for (int off = 4; off > 0; off >>= 1)
        #pragma unroll
        for (int i = 0; i < 4; ++i) {
            lsB[i] += __shfl_down(lsB[i], off);
            lqB[i] += __shfl_down(lqB[i], off);
        }
    if (kg == 0)
        #pragma unroll
        for (int i = 0; i < 4; ++i) {
            atomicAdd(&dsum[o0 + i], (double)lsB[i]);
            atomicAdd(&dsq[o0 + i], (double)lqB[i]);
        }
}

// ---------------- Stage 2 ----------------
constexpr int LDK2 = 68;  // 64 k + 4 pad (keeps b128 alignment of rows)

// Gather tile in transposed layout xT[c][k] (c=0..133).
DEVI void s2_gatherT(int t, int bs, const float* xyz1, const float* xyz2,
                     const int* ni2, const float* f1, float* xT) {
    int b = bs >> 7;
    float cx = xyz2[bs * 3 + 0], cy = xyz2[bs * 3 + 1], cz = xyz2[bs * 3 + 2];
    for (int idx = t; idx < K2 * 134; idx += 512) {
        int k = idx / 134, c = idx - k * 134;
        int j = ni2[bs * K2 + k];
        const float* p1 = xyz1 + ((size_t)b * S1 + j) * 3;
        float v;
        if (c < 3)      v = p1[c] - (c == 0 ? cx : (c == 1 ? cy : cz));
        else if (c < 6) v = p1[c - 3];
        else            v = f1[((size_t)b * S1 + j) * 128 + (c - 6)];
        xT[c * LDK2 + k] = v;
    }
}

// Stats of y2a (C=134 -> O=128). Tile 4o x 4k; w2aT from global (L2-hot broadcast).
__global__ __launch_bounds__(512, 4)
void k_s2_statsA(const float* __restrict__ xyz1, const float* __restrict__ xyz2,
                 const int* __restrict__ ni2, const float* __restrict__ f1,
                 const float* __restrict__ w2aT,
                 double* __restrict__ dsum, double* __restrict__ dsq) {
    __shared__ float xT[134 * LDK2];   // 36.4 KB only -> 4 blocks/CU
    int t = threadIdx.x;
    int og = t >> 4, kg = t & 15;      // 32 x 16
    int o0 = og * 4, k0 = kg * 4;
    float ls[4] = {0.f, 0.f, 0.f, 0.f}, lq[4] = {0.f, 0.f, 0.f, 0.f};
    for (int bs = blockIdx.x; bs < Bb * S2; bs += gridDim.x) {
        __syncthreads();
        s2_gatherT(t, bs, xyz1, xyz2, ni2, f1, xT);
        __syncthreads();
        float acc[16];
        #pragma unroll
        for (int i = 0; i < 16; ++i) acc[i] = 0.f;
        for (int c = 0; c < 134; ++c) {
            float4 wv = *(const float4*)&w2aT[c * 128 + o0];
            float4 xv = *(const float4*)&xT[c * LDK2 + k0];
            float ws[4] = {wv.x, wv.y, wv.z, wv.w};
            float xs[4] = {xv.x, xv.y, xv.z, xv.w};
            #pragma unroll
            for (int i = 0; i < 4; ++i)
                #pragma unroll
                for (int j = 0; j < 4; ++j)
                    acc[i * 4 + j] = fmaf(ws[i], xs[j], acc[i * 4 + j]);
        }
        #pragma unroll
        for (int i = 0; i < 4; ++i)
            #pragma unroll
            for (int j = 0; j < 4; ++j) {
                float y = acc[i * 4 + j];
                ls[i] += y; lq[i] += y * y;
            }
    }
    #pragma unroll
    for (int off = 8; off > 0; off >>= 1)
        #pragma unroll
        for (int i = 0; i < 4; ++i) {
            ls[i] += __shfl_down(ls[i], off);
            lq[i] += __shfl_down(lq[i], off);
        }
    if (kg == 0)
        #pragma unroll
        for (int i = 0; i < 4; ++i) {
            atomicAdd(&dsum[o0 + i], (double)ls[i]);
            atomicAdd(&dsq[o0 + i], (double)lq[i]);
        }
}

// Main stage-2: A: y2a (4o x 4k regs, w2aT global) -> x2T LDS;
// B: y2b (128->512) tile 4o x 16k, w2bT global broadcast; stats + minmax.
// LDS 71 KB -> 2 blocks/CU; no weight staging (the round-4 16-way-conflict source).
__global__ __launch_bounds__(512, 4)
void k_s2_main(const float* __restrict__ xyz1, const float* __restrict__ xyz2,
               const int* __restrict__ ni2, const float* __restrict__ f1,
               const float* __restrict__ w2aT,
               const float* __restrict__ m2a, const float* __restrict__ s2a,
               const float* __restrict__ beta2a, const float* __restrict__ w2bT,
               double* __restrict__ dsum, double* __restrict__ dsq,
               float* __restrict__ gmx, float* __restrict__ gmn) {
    __shared__ float xT[134 * LDK2];    // 36.4 KB gather tile
    __shared__ float x2T[128 * LDK2];   // 34.8 KB x2 [c2][k]
    int t = threadIdx.x;
    int ogA = t >> 4, kgA = t & 15;    // A: 32 x 16 -> 4o x 4k
    int o0A = ogA * 4, k0A = kgA * 4;
    int ogB = t >> 2, kgB = t & 3;     // B: 128 x 4 -> 4o x 16k
    int o0B = ogB * 4, k0B = kgB * 16;
    float lsB[4] = {0.f, 0.f, 0.f, 0.f}, lqB[4] = {0.f, 0.f, 0.f, 0.f};
    for (int bs = blockIdx.x; bs < Bb * S2; bs += gridDim.x) {
        __syncthreads();  // protect xT from previous iteration's B reads? (B reads x2T only) — protects gather vs prior A reads
        s2_gatherT(t, bs, xyz1, xyz2, ni2, f1, xT);
        __syncthreads();
        // A: y2a tile
        float acc[16];
        #pragma unroll
        for (int i = 0; i < 16; ++i) acc[i] = 0.f;
        for (int c = 0; c < 134; ++c) {
            float4 wv = *(const float4*)&w2aT[c * 128 + o0A];
            float4 xv = *(const float4*)&xT[c * LDK2 + k0A];
            float ws[4] = {wv.x, wv.y, wv.z, wv.w};
            float xs[4] = {xv.x, xv.y, xv.z, xv.w};
            #pragma unroll
            for (int i = 0; i < 4; ++i)
                #pragma unroll
                for (int j = 0; j < 4; ++j)
                    acc[i * 4 + j] = fmaf(ws[i], xs[j], acc[i * 4 + j]);
        }
        float4 mam = *(const float4*)&m2a[o0A];
        float4 sam = *(const float4*)&s2a[o0A];
        float4 bam = *(const float4*)&beta2a[o0A];
        float ma[4] = {mam.x, mam.y, mam.z, mam.w};
        float sa[4] = {sam.x, sam.y, sam.z, sam.w};
        float ba[4] = {bam.x, bam.y, bam.z, bam.w};
        #pragma unroll
        for (int i = 0; i < 4; ++i) {
            float4 v;
            v.x = fmaxf((acc[i * 4 + 0] - ma[i]) * sa[i] + ba[i], 0.f);
            v.y = fmaxf((acc[i * 4 + 1] - ma[i]) * sa[i] + ba[i], 0.f);
            v.z = fmaxf((acc[i * 4 + 2] - ma[i]) * sa[i] + ba[i], 0.f);
            v.w = fmaxf((acc[i * 4 + 3] - ma[i]) * sa[i] + ba[i], 0.f);
            *(float4*)&x2T[(o0A + i) * LDK2 + k0A] = v;
        }
        __syncthreads();
        // B: y2b tile 4o x 16k; w from global w2bT (wave reads 256B contiguous, L2-hot)
        float accB[64];
        #pragma unroll
        for (int i = 0; i < 64; ++i) accB[i] = 0.f;
        for (int c = 0; c < 128; ++c) {
            float4 wv = *(const float4*)&w2bT[c * 512 + o0B];
            const float* xr = &x2T[c * LDK2 + k0B];
            float4 x0 = *(const float4*)(xr);
            float4 x1 = *(const float4*)(xr + 4);
            float4 x2 = *(const float4*)(xr + 8);
            float4 x3 = *(const float4*)(xr + 12);
            float ws[4] = {wv.x, wv.y, wv.z, wv.w};
            float xs[16] = {x0.x, x0.y, x0.z, x0.w, x1.x, x1.y, x1.z, x1.w,
                            x2.x, x2.y, x2.z, x2.w, x3.x, x3.y, x3.z, x3.w};
            #pragma unroll
            for (int i = 0; i < 4; ++i)
                #pragma unroll
                for (int j = 0; j < 16; ++j)
                    accB[i * 16 + j] = fmaf(ws[i], xs[j], accB[i * 16 + j]);
        }
        float mxB[4], mnB[4];
        #pragma unroll
        for (int i = 0; i < 4; ++i) {
            mxB[i] = -1e30f; mnB[i] = 1e30f;
            #pragma unroll
            for (int j = 0; j < 16; ++j) {
                float y = accB[i * 16 + j];
                lsB[i] += y; lqB[i] += y * y;
                mxB[i] = fmaxf(mxB[i], y); mnB[i] = fminf(mnB[i], y);
            }
        }
        #pragma unroll
        for (int off = 2; off > 0; off >>= 1)
            #pragma unroll
            for (int i = 0; i < 4; ++i) {
                mxB[i] = fmaxf(mxB[i], __shfl_down(mxB[i], off));
                mnB[i] = fminf(mnB[i], __shfl_down(mnB[i], off));
            }
        if (kgB == 0) {
            *(float4*)&gmx[(size_t)bs * 512 + o0B] = make_float4(mxB[0], mxB[1], mxB[2], mxB[3]);
            *(float4*)&gmn[(size_t)bs * 512 + o0B] = make_float4(mnB[0], mnB[1], mnB[2], mnB[3]);
        }
    }
    #pragma unroll
    for (int off = 2; off > 0; off >>= 1)
        #pragma unroll
        for (int i = 0; i < 4; ++i) {
            lsB[i] += __shfl_down(lsB[i], off);
            lqB[i] += __shfl_down(lqB[i], off);
        }
    if (kgB == 0)
        #pragma unroll
        for (int i = 0; i < 4; ++i) {
            atomicAdd(&dsum[o0B + i], (double)lsB[i]);
            atomicAdd(&dsq[o0B + i], (double)lqB[i]);
        }
}

// ---------------- Stage 3 ----------------
constexpr int X3_LD = 520;  // 515 real + 5 zero pad

__global__ __launch_bounds__(512)
void k_s3(const float* __restrict__ xyz2, const float* __restrict__ f2,
          const float* __restrict__ w3, double* __restrict__ dsum,
          double* __restrict__ dsq, float* __restrict__ gmx, float* __restrict__ gmn) {
    __shared__ float xt[16 * X3_LD];  // 33.3 KB
    int b = blockIdx.x >> 3, kc = blockIdx.x & 7;
    int t = threadIdx.x;  // = o
    for (int idx = t; idx < 16 * X3_LD; idx += 512) {
        int rr = idx / X3_LD, c = idx - rr * X3_LD;
        int row = b * S2 + kc * 16 + rr;
        float v;
        if (c < 3)        v = xyz2[row * 3 + c];
        else if (c < 515) v = f2[(size_t)row * 512 + (c - 3)];
        else              v = 0.f;
        xt[idx] = v;
    }
    __syncthreads();
    float acc[16];
    #pragma unroll
    for (int rr = 0; rr < 16; ++rr) acc[rr] = 0.f;
    for (int ct = 0; ct < 16; ++ct) {
        float wr[32];
        #pragma unroll
        for (int i = 0; i < 32; ++i) wr[i] = w3[(size_t)t * 515 + ct * 32 + i];
        #pragma unroll
        for (int rr = 0; rr < 16; ++rr) {
            const float* xr = &xt[rr * X3_LD + ct * 32];
            #pragma unroll
            for (int j = 0; j < 8; ++j) {
                float4 x = *(const float4*)(xr + 4 * j);
                acc[rr] = fmaf(x.x, wr[4 * j + 0], acc[rr]);
                acc[rr] = fmaf(x.y, wr[4 * j + 1], acc[rr]);
                acc[rr] = fmaf(x.z, wr[4 * j + 2], acc[rr]);
                acc[rr] = fmaf(x.w, wr[4 * j + 3], acc[rr]);
            }
        }
    }
    {
        float wr[8];
        #pragma unroll
        for (int i = 0; i < 8; ++i) wr[i] = (i < 3) ? w3[(size_t)t * 515 + 512 + i] : 0.f;
        #pragma unroll
        for (int rr = 0; rr < 16; ++rr) {
            const float* xr = &xt[rr * X3_LD + 512];
            #pragma unroll
            for (int j = 0; j < 2; ++j) {
                float4 x = *(const float4*)(xr + 4 * j);
                acc[rr] = fmaf(x.x, wr[4 * j + 0], acc[rr]);
                acc[rr] = fmaf(x.y, wr[4 * j + 1], acc[rr]);
                acc[rr] = fmaf(x.z, wr[4 * j + 2], acc[rr]);
                acc[rr] = fmaf(x.w, wr[4 * j + 3], acc[rr]);
            }
        }
    }
    float ls = 0.f, lsq = 0.f, mxv = -1e30f, mnv = 1e30f;
    #pragma unroll
    for (int rr = 0; rr < 16; ++rr) {
        float y = acc[rr];
        ls += y; lsq += y * y;
        mxv = fmaxf(mxv, y); mnv = fminf(mnv, y);
    }
    atomicAdd(&dsum[t], (double)ls);
    atomicAdd(&dsq[t], (double)lsq);
    gmx[(size_t)blockIdx.x * 512 + t] = mxv;
    gmn[(size_t)blockIdx.x * 512 + t] = mnv;
}

__global__ void k_apply3(const float* __restrict__ gmx, const float* __restrict__ gmn,
                         const float* __restrict__ m, const float* __restrict__ s,
                         const float* __restrict__ beta, float* __restrict__ out) {
    int i = blockIdx.x * blockDim.x + threadIdx.x;
    if (i >= Bb * 512) return;
    int b = i >> 9, o = i & 511;
    float mx = -1e30f, mn = 1e30f;
    for (int ch = 0; ch < 8; ++ch) {
        mx = fmaxf(mx, gmx[(size_t)(b * 8 + ch) * 512 + o]);
        mn = fminf(mn, gmn[(size_t)(b * 8 + ch) * 512 + o]);
    }
    float sc = s[o];
    float pick = (sc >= 0.f) ? mx : mn;
    out[i] = fmaxf((pick - m[o]) * sc + beta[o], 0.f);
}

static inline size_t align256(size_t x) { return (x + 255) & ~(size_t)255; }

extern "C" void kernel_launch(void* const* d_in, const int* in_sizes, int n_in,
                              void* d_out, int out_size, void* d_ws, size_t ws_size,
                              hipStream_t stream) {
    const float* pc  = (const float*)d_in[0];
    const float* w1a = (const float*)d_in[1];
    const float* g1a = (const float*)d_in[2];
    const float* b1a = (const float*)d_in[3];
    const float* w1b = (const float*)d_in[4];
    const float* g1b = (const float*)d_in[5];
    const float* b1b = (const float*)d_in[6];
    const float* w2a = (const float*)d_in[7];
    const float* g2a = (const float*)d_in[8];
    const float* b2a = (const float*)d_in[9];
    const float* w2b = (const float*)d_in[10];
    const float* g2b = (const float*)d_in[11];
    const float* b2b = (const float*)d_in[12];
    const float* w3  = (const float*)d_in[13];
    const float* g3  = (const float*)d_in[14];
    const float* b3  = (const float*)d_in[15];
    float* out = (float*)d_out;

    char* ws = (char*)d_ws;
    size_t off = 0;
    auto alloc = [&](size_t bytes) { void* p = ws + off; off += align256(bytes); return p; };

    float* xyz   = (float*)alloc(sizeof(float) * Bb * Nn * 3);
    float* xyz1  = (float*)alloc(sizeof(float) * Bb * S1 * 3);
    float* xyz2  = (float*)alloc(sizeof(float) * Bb * S2 * 3);
    int*   ni1   = (int*)alloc(sizeof(int) * Bb * S1 * K1);
    int*   ni2   = (int*)alloc(sizeof(int) * Bb * S2 * K2);
    float* gmx1  = (float*)alloc(sizeof(float) * (size_t)Bb * S1 * 128);  // f1 after apply
    float* gmn1  = (float*)alloc(sizeof(float) * (size_t)Bb * S1 * 128);
    float* gmx2  = (float*)alloc(sizeof(float) * (size_t)Bb * S2 * 512);  // f2 after apply
    float* gmn2  = (float*)alloc(sizeof(float) * (size_t)Bb * S2 * 512);
    float* gmx3  = (float*)alloc(sizeof(float) * 256 * 512);
    float* gmn3  = (float*)alloc(sizeof(float) * 256 * 512);
    float* w2aT  = (float*)alloc(sizeof(float) * 134 * 128);
    float* w2bT  = (float*)alloc(sizeof(float) * 128 * 512);
    double* dsum = (double*)alloc(sizeof(double) * 512);
    double* dsq  = (double*)alloc(sizeof(double) * 512);
    float* m1a = (float*)alloc(sizeof(float) * 64);
    float* s1a = (float*)alloc(sizeof(float) * 64);
    float* m1b = (float*)alloc(sizeof(float) * 128);
    float* s1b = (float*)alloc(sizeof(float) * 128);
    float* m2a = (float*)alloc(sizeof(float) * 128);
    float* s2a = (float*)alloc(sizeof(float) * 128);
    float* m2b = (float*)alloc(sizeof(float) * 512);
    float* s2b = (float*)alloc(sizeof(float) * 512);
    float* m3  = (float*)alloc(sizeof(float) * 512);
    float* s3  = (float*)alloc(sizeof(float) * 512);
    float* f1 = gmx1;  // in-place apply
    float* f2 = gmx2;

    // ---- Stage 1 ----
    k_transpose<<<(Bb * Nn + 255) / 256, 256, 0, stream>>>(pc, xyz);
    k_wtrans<<<256, 256, 0, stream>>>(w2a, w2b, w2aT, w2bT);
    k_fps<<<Bb, 256, 0, stream>>>(xyz, Nn, S1, xyz1);
    k_ballquery<<<(Bb * S1 + 255) / 256, 256, 0, stream>>>(xyz, xyz1, Nn, S1, K1,
                                                           (float)(0.23 * 0.23), ni1);
    k_zero_stats<<<2, 256, 0, stream>>>(dsum, dsq, 512);
    k_s1_statsA<<<2048, 256, 0, stream>>>(xyz, xyz1, ni1, w1a, dsum, dsq);
    k_finalize<<<2, 256, 0, stream>>>(dsum, dsq, g1a, m1a, s1a, 64,
                                      1.0 / ((double)Bb * S1 * K1));
    k_zero_stats<<<2, 256, 0, stream>>>(dsum, dsq, 512);
    k_s1_main<<<1024, 256, 0, stream>>>(xyz, xyz1, ni1, w1a, m1a, s1a, b1a, w1b,
                                        dsum, dsq, gmx1, gmn1);
    k_finalize<<<2, 256, 0, stream>>>(dsum, dsq, g1b, m1b, s1b, 128,
                                      1.0 / ((double)Bb * S1 * K1));
    {
        long long tot = (long long)Bb * S1 * 128;
        k_applyMM<<<(int)((tot + 255) / 256), 256, 0, stream>>>(gmx1, gmn1, m1b, s1b, b1b,
                                                                f1, tot, 128);
    }
    // ---- Stage 2 ----
    k_fps<<<Bb, 256, 0, stream>>>(xyz1, S1, S2, xyz2);
    k_ballquery<<<(Bb * S2 + 255) / 256, 256, 0, stream>>>(xyz1, xyz2, S1, S2, K2,
                                                           (float)(0.32 * 0.32), ni2);
    k_zero_stats<<<2, 256, 0, stream>>>(dsum, dsq, 512);
    k_s2_statsA<<<1024, 512, 0, stream>>>(xyz1, xyz2, ni2, f1, w2aT, dsum, dsq);
    k_finalize<<<2, 256, 0, stream>>>(dsum, dsq, g2a, m2a, s2a, 128,
                                      1.0 / ((double)Bb * S2 * K2));
    k_zero_stats<<<2, 256, 0, stream>>>(dsum, dsq, 512);
    k_s2_main<<<1024, 512, 0, stream>>>(xyz1, xyz2, ni2, f1, w2aT, m2a, s2a, b2a, w2bT,
                                        dsum, dsq, gmx2, gmn2);
    k_finalize<<<2, 256, 0, stream>>>(dsum, dsq, g2b, m2b, s2b, 512,
                                      1.0 / ((double)Bb * S2 * K2));
    {
        long long tot = (long long)Bb * S2 * 512;
        k_applyMM<<<(int)((tot + 255) / 256), 256, 0, stream>>>(gmx2, gmn2, m2b, s2b, b2b,
                                                                f2, tot, 512);
    }
    // ---- Stage 3 ----
    k_zero_stats<<<2, 256, 0, stream>>>(dsum, dsq, 512);
    k_s3<<<256, 512, 0, stream>>>(xyz2, f2, w3, dsum, dsq, gmx3, gmn3);
    k_finalize<<<2, 256, 0, stream>>>(dsum, dsq, g3, m3, s3, 512,
                                      1.0 / ((double)Bb * S2));
    k_apply3<<<(Bb * 512 + 255) / 256, 256, 0, stream>>>(gmx3, gmn3, m3, s3, b3, out);
}

// Round 6
// 1992.897 us; speedup vs baseline: 4.5355x; 1.4289x over previous
//
#include <hip/hip_runtime.h>
#include <math.h>

constexpr int Bb = 32, Nn = 2048;
constexpr int S1 = 512, K1 = 48;
constexpr int S2 = 128, K2 = 64;

#define DEVI __device__ __forceinline__

// Exact (non-FMA-contracted) squared distance, matches numpy ((dx^2+dy^2)+dz^2) fp32.
DEVI float sq3(float dx, float dy, float dz) {
    return __fadd_rn(__fadd_rn(__fmul_rn(dx, dx), __fmul_rn(dy, dy)), __fmul_rn(dz, dz));
}

// pc (B,3,N) -> xyz (B,N,3)
__global__ void k_transpose(const float* __restrict__ pc, float* __restrict__ xyz) {
    int i = blockIdx.x * blockDim.x + threadIdx.x;
    if (i >= Bb * Nn) return;
    int b = i / Nn;
    const float* s = pc + (size_t)b * 3 * Nn + (i % Nn);
    float* d = xyz + (size_t)i * 3;
    d[0] = s[0];
    d[1] = s[Nn];
    d[2] = s[2 * Nn];
}

// Transpose stage-2 weights into [c][o] layout (one-time, tiny).
__global__ void k_wtrans(const float* __restrict__ w2a, const float* __restrict__ w2b,
                         float* __restrict__ w2aT, float* __restrict__ w2bT) {
    int i = blockIdx.x * blockDim.x + threadIdx.x;
    if (i < 134 * 128) {
        int c = i >> 7, o = i & 127;
        w2aT[i] = w2a[(size_t)o * 134 + c];
    }
    if (i < 128 * 512) {
        int c = i >> 9, o = i & 511;
        w2bT[i] = w2b[(size_t)o * 128 + c];
    }
}

// FPS, latency-optimized: one block (4 waves) per batch; dist in registers;
// wave-level shuffle argmax (no barriers) + 4-entry cross-wave exchange (2 barriers/iter).
// Selection is bitwise-identical to numpy: exact fp32 distances, global
// first-occurrence argmax via strict-> within ascending per-lane scan + index tie-break.
template <int PTS>
__global__ __launch_bounds__(256)
void k_fps_fast(const float* __restrict__ pts, int npoint, float* __restrict__ sel) {
    constexpr int N = PTS * 256;
    __shared__ float px[N], py[N], pz[N];
    __shared__ float rv[4];
    __shared__ int ri[4];
    int b = blockIdx.x, t = threadIdx.x;
    const float* base = pts + (size_t)b * N * 3;
    float dist[PTS];
    #pragma unroll
    for (int i = 0; i < PTS; ++i) {
        int j = i * 256 + t;
        px[j] = base[j * 3 + 0];
        py[j] = base[j * 3 + 1];
        pz[j] = base[j * 3 + 2];
        dist[i] = 1e10f;
    }
    if (t == 0) {
        float* o = sel + (size_t)b * npoint * 3;
        o[0] = base[0]; o[1] = base[1]; o[2] = base[2];
    }
    __syncthreads();
    float lx = px[0], ly = py[0], lz = pz[0];
    for (int it = 1; it < npoint; ++it) {
        float bv = -1.0f;
        int bi = 0;
        #pragma unroll
        for (int i = 0; i < PTS; ++i) {
            int j = i * 256 + t;
            float d = sq3(px[j] - lx, py[j] - ly, pz[j] - lz);
            float dd = fminf(dist[i], d);
            dist[i] = dd;
            if (dd > bv) { bv = dd; bi = j; }  // ascending j per lane: strict > = first occurrence
        }
        #pragma unroll
        for (int off = 32; off > 0; off >>= 1) {
            float ov = __shfl_down(bv, off);
            int oi = __shfl_down(bi, off);
            if (ov > bv || (ov == bv && oi < bi)) { bv = ov; bi = oi; }
        }
        __syncthreads();  // previous iteration's rv/ri reads complete
        if ((t & 63) == 0) { rv[t >> 6] = bv; ri[t >> 6] = bi; }
        __syncthreads();
        float v0 = rv[0];
        int i0 = ri[0];
        #pragma unroll
        for (int w = 1; w < 4; ++w) {
            float vw = rv[w]; int iw = ri[w];
            if (vw > v0 || (vw == v0 && iw < i0)) { v0 = vw; i0 = iw; }
        }
        lx = px[i0]; ly = py[i0]; lz = pz[i0];
        if (t == 0) {
            float* o = sel + ((size_t)b * npoint + it) * 3;
            o[0] = lx; o[1] = ly; o[2] = lz;
        }
    }
}

// Ball query, one wave per center: 64 candidates/step via ballot + popcount prefix.
// Hits are written in ascending-index order == reference's sort-based semantics.
__global__ void k_ballquery_w(const float* __restrict__ src, const float* __restrict__ ctr,
                              int n, int m, int nsample, float r2, int* __restrict__ out) {
    int wid = blockIdx.x * (blockDim.x >> 6) + (threadIdx.x >> 6);
    int lane = threadIdx.x & 63;
    if (wid >= Bb * m) return;
    int b = wid / m;
    const float* sb = src + (size_t)b * n * 3;
    float cx = ctr[(size_t)wid * 3 + 0];
    float cy = ctr[(size_t)wid * 3 + 1];
    float cz = ctr[(size_t)wid * 3 + 2];
    int* ob = out + (size_t)wid * nsample;
    int cnt = 0, first = 0;
    for (int j0 = 0; j0 < n && cnt < nsample; j0 += 64) {
        int j = j0 + lane;
        float d2 = sq3(sb[j * 3 + 0] - cx, sb[j * 3 + 1] - cy, sb[j * 3 + 2] - cz);
        bool hit = d2 < r2;
        unsigned long long mask = __ballot(hit);
        if (cnt == 0 && mask) first = j0 + __ffsll(mask) - 1;
        int pos = cnt + __popcll(mask & ((1ull << lane) - 1ull));
        if (hit && pos < nsample) ob[pos] = j;
        cnt += __popcll(mask);
    }
    if (cnt < nsample)
        for (int k = cnt + lane; k < nsample; k += 64) ob[k] = first;
}

__global__ void k_zero_stats(double* dsum, double* dsq, int O) {
    int i = blockIdx.x * blockDim.x + threadIdx.x;
    if (i < O) { dsum[i] = 0.0; dsq[i] = 0.0; }
}

__global__ void k_finalize(const double* __restrict__ dsum, const double* __restrict__ dsq,
                           const float* __restrict__ g, float* __restrict__ mean,
                           float* __restrict__ scale, int O, double inv_count) {
    int o = blockIdx.x * blockDim.x + threadIdx.x;
    if (o < O) {
        double m = dsum[o] * inv_count;
        double v = dsq[o] * inv_count - m * m;
        mean[o] = (float)m;
        scale[o] = (float)((double)g[o] / sqrt(v + 1e-5));
    }
}

// Apply norm+relu to pooled minmax (in-place capable: f may alias gmx).
__global__ void k_applyMM(const float* __restrict__ gmx, const float* __restrict__ gmn,
                          const float* __restrict__ m, const float* __restrict__ s,
                          const float* __restrict__ beta, float* __restrict__ f,
                          long long total, int O) {
    long long i = (long long)blockIdx.x * blockDim.x + threadIdx.x;
    if (i >= total) return;
    int o = (int)(i % O);
    float sc = s[o];
    float pick = (sc >= 0.f) ? gmx[i] : gmn[i];
    f[i] = fmaxf((pick - m[o]) * sc + beta[o], 0.f);
}

// ---------------- Stage 1 ----------------
// Stats of y1a (C=6 -> O=64) over all (b,s,k).
__global__ __launch_bounds__(256)
void k_s1_statsA(const float* __restrict__ xyz, const float* __restrict__ xyz1,
                 const int* __restrict__ ni1, const float* __restrict__ w1a,
                 double* __restrict__ dsum, double* __restrict__ dsq) {
    __shared__ float red[256], red2[256];
    int t = threadIdx.x;
    float ls = 0.f, lsq = 0.f;
    for (int bs = blockIdx.x; bs < Bb * S1; bs += gridDim.x) {
        int b = bs >> 9;
        float cx = xyz1[bs * 3 + 0], cy = xyz1[bs * 3 + 1], cz = xyz1[bs * 3 + 2];
        for (int idx = t; idx < K1 * 64; idx += 256) {
            int k = idx >> 6, c = idx & 63;
            int j = ni1[bs * K1 + k];
            const float* g = xyz + ((size_t)b * Nn + j) * 3;
            float gx = g[0], gy = g[1], gz = g[2];
            const float* w = w1a + c * 6;
            float y = (gx - cx) * w[0] + (gy - cy) * w[1] + (gz - cz) * w[2]
                    + gx * w[3] + gy * w[4] + gz * w[5];
            ls += y; lsq += y * y;
        }
    }
    red[t] = ls; red2[t] = lsq;
    __syncthreads();
    if (t < 64) {
        double S = (double)red[t] + red[t + 64] + red[t + 128] + red[t + 192];
        double Q = (double)red2[t] + red2[t + 64] + red2[t + 128] + red2[t + 192];
        atomicAdd(&dsum[t], S); atomicAdd(&dsq[t], Q);
    }
}

// Main stage-1: x1 = relu(norm(y1a)); y1b (64->128): stats + per-(bs,o) max/min.
constexpr int LDK1 = 50;  // 48 k + 2 pad
__global__ __launch_bounds__(256)
void k_s1_main(const float* __restrict__ xyz, const float* __restrict__ xyz1,
               const int* __restrict__ ni1, const float* __restrict__ w1a,
               const float* __restrict__ m1a, const float* __restrict__ s1a,
               const float* __restrict__ beta1a, const float* __restrict__ w1b,
               double* __restrict__ dsum, double* __restrict__ dsq,
               float* __restrict__ gmx, float* __restrict__ gmn) {
    __shared__ float x1T[64 * LDK1];   // 12.8 KB  [c][k]
    __shared__ float wT[64 * 128];     // 32 KB    [c][o]
    int t = threadIdx.x;
    int og = t >> 3, kg = t & 7;       // 32 o-groups x 8 k-groups
    int o0 = og * 4, k0 = kg * 6;
    for (int idx = t; idx < 64 * 128; idx += 256)
        wT[idx] = w1b[(size_t)(idx & 127) * 64 + (idx >> 7)];
    __syncthreads();
    float lsB[4] = {0.f, 0.f, 0.f, 0.f}, lqB[4] = {0.f, 0.f, 0.f, 0.f};
    for (int bs = blockIdx.x; bs < Bb * S1; bs += gridDim.x) {
        int b = bs >> 9;
        float cx = xyz1[bs * 3 + 0], cy = xyz1[bs * 3 + 1], cz = xyz1[bs * 3 + 2];
        // A: y1a -> x1T[c][k]
        #pragma unroll
        for (int i = 0; i < 12; ++i) {
            int idx = t + i * 256;
            int k = idx >> 6, c = idx & 63;
            int j = ni1[bs * K1 + k];
            const float* g = xyz + ((size_t)b * Nn + j) * 3;
            float gx = g[0], gy = g[1], gz = g[2];
            const float* w = w1a + c * 6;
            float y = (gx - cx) * w[0] + (gy - cy) * w[1] + (gz - cz) * w[2]
                    + gx * w[3] + gy * w[4] + gz * w[5];
            x1T[c * LDK1 + k] = fmaxf((y - m1a[c]) * s1a[c] + beta1a[c], 0.f);
        }
        __syncthreads();
        // B: y1b tile 4o x 6k
        float acc[24];
        #pragma unroll
        for (int i = 0; i < 24; ++i) acc[i] = 0.f;
        for (int c = 0; c < 64; ++c) {
            float4 wv = *(const float4*)&wT[c * 128 + o0];
            float2 xa = *(const float2*)&x1T[c * LDK1 + k0];
            float2 xb = *(const float2*)&x1T[c * LDK1 + k0 + 2];
            float2 xc = *(const float2*)&x1T[c * LDK1 + k0 + 4];
            float xs[6] = {xa.x, xa.y, xb.x, xb.y, xc.x, xc.y};
            float ws[4] = {wv.x, wv.y, wv.z, wv.w};
            #pragma unroll
            for (int i = 0; i < 4; ++i)
                #pragma unroll
                for (int j = 0; j < 6; ++j)
                    acc[i * 6 + j] = fmaf(ws[i], xs[j], acc[i * 6 + j]);
        }
        float mx[4], mn[4];
        #pragma unroll
        for (int i = 0; i < 4; ++i) {
            mx[i] = -1e30f; mn[i] = 1e30f;
            #pragma unroll
            for (int j = 0; j < 6; ++j) {
                float y = acc[i * 6 + j];
                lsB[i] += y; lqB[i] += y * y;
                mx[i] = fmaxf(mx[i], y); mn[i] = fminf(mn[i], y);
            }
        }
        #pragma unroll
        for (int off = 4; off > 0; off >>= 1)
            #pragma unroll
            for (int i = 0; i < 4; ++i) {
                mx[i] = fmaxf(mx[i], __shfl_down(mx[i], off));
                mn[i] = fminf(mn[i], __shfl_down(mn[i], off));
            }
        if (kg == 0) {
            *(float4*)&gmx[(size_t)bs * 128 + o0] = make_float4(mx[0], mx[1], mx[2], mx[3]);
            *(float4*)&gmn[(size_t)bs * 128 + o0] = make_float4(mn[0], mn[1], mn[2], mn[3]);
        }
        __syncthreads();
    }
    #pragma unroll
    for (int off = 4; off > 0; off >>= 1)
        #pragma unroll
        for (int i = 0; i < 4; ++i) {
            lsB[i] += __shfl_down(lsB[i], off);
            lqB[i] += __shfl_down(lqB[i], off);
        }
    if (kg == 0)
        #pragma unroll
        for (int i = 0; i < 4; ++i) {
            atomicAdd(&dsum[o0 + i], (double)lsB[i]);
            atomicAdd(&dsq[o0 + i], (double)lqB[i]);
        }
}

// ---------------- Stage 2 ----------------
constexpr int LDK2 = 68;  // 64 k + 4 pad

// Gather tile in transposed layout xT[c][k] (c=0..133).
DEVI void s2_gatherT(int t, int bs, const float* xyz1, const float* xyz2,
                     const int* ni2, const float* f1, float* xT) {
    int b = bs >> 7;
    float cx = xyz2[bs * 3 + 0], cy = xyz2[bs * 3 + 1], cz = xyz2[bs * 3 + 2];
    for (int idx = t; idx < K2 * 134; idx += 512) {
        int k = idx / 134, c = idx - k * 134;
        int j = ni2[bs * K2 + k];
        const float* p1 = xyz1 + ((size_t)b * S1 + j) * 3;
        float v;
        if (c < 3)      v = p1[c] - (c == 0 ? cx : (c == 1 ? cy : cz));
        else if (c < 6) v = p1[c - 3];
        else            v = f1[((size_t)b * S1 + j) * 128 + (c - 6)];
        xT[c * LDK2 + k] = v;
    }
}

// Stats of y2a (C=134 -> O=128). Tile 4o x 4k; w2aT from global (L2-hot broadcast).
__global__ __launch_bounds__(512, 4)
void k_s2_statsA(const float* __restrict__ xyz1, const float* __restrict__ xyz2,
                 const int* __restrict__ ni2, const float* __restrict__ f1,
                 const float* __restrict__ w2aT,
                 double* __restrict__ dsum, double* __restrict__ dsq) {
    __shared__ float xT[134 * LDK2];   // 36.4 KB
    int t = threadIdx.x;
    int og = t >> 4, kg = t & 15;      // 32 x 16
    int o0 = og * 4, k0 = kg * 4;
    float ls[4] = {0.f, 0.f, 0.f, 0.f}, lq[4] = {0.f, 0.f, 0.f, 0.f};
    for (int bs = blockIdx.x; bs < Bb * S2; bs += gridDim.x) {
        __syncthreads();
        s2_gatherT(t, bs, xyz1, xyz2, ni2, f1, xT);
        __syncthreads();
        float acc[16];
        #pragma unroll
        for (int i = 0; i < 16; ++i) acc[i] = 0.f;
        for (int c = 0; c < 134; ++c) {
            float4 wv = *(const float4*)&w2aT[c * 128 + o0];
            float4 xv = *(const float4*)&xT[c * LDK2 + k0];
            float ws[4] = {wv.x, wv.y, wv.z, wv.w};
            float xs[4] = {xv.x, xv.y, xv.z, xv.w};
            #pragma unroll
            for (int i = 0; i < 4; ++i)
                #pragma unroll
                for (int j = 0; j < 4; ++j)
                    acc[i * 4 + j] = fmaf(ws[i], xs[j], acc[i * 4 + j]);
        }
        #pragma unroll
        for (int i = 0; i < 4; ++i)
            #pragma unroll
            for (int j = 0; j < 4; ++j) {
                float y = acc[i * 4 + j];
                ls[i] += y; lq[i] += y * y;
            }
    }
    #pragma unroll
    for (int off = 8; off > 0; off >>= 1)
        #pragma unroll
        for (int i = 0; i < 4; ++i) {
            ls[i] += __shfl_down(ls[i], off);
            lq[i] += __shfl_down(lq[i], off);
        }
    if (kg == 0)
        #pragma unroll
        for (int i = 0; i < 4; ++i) {
            atomicAdd(&dsum[o0 + i], (double)ls[i]);
            atomicAdd(&dsq[o0 + i], (double)lq[i]);
        }
}

// Main stage-2: A: y2a (4o x 4k regs, w2aT global) -> x2T LDS;
// B: y2b (128->512) tile 4o x 16k, w2bT global broadcast; stats + minmax.
__global__ __launch_bounds__(512, 4)
void k_s2_main(const float* __restrict__ xyz1, const float* __restrict__ xyz2,
               const int* __restrict__ ni2, const float* __restrict__ f1,
               const float* __restrict__ w2aT,
               const float* __restrict__ m2a, const float* __restrict__ s2a,
               const float* __restrict__ beta2a, const float* __restrict__ w2bT,
               double* __restrict__ dsum, double* __restrict__ dsq,
               float* __restrict__ gmx, float* __restrict__ gmn) {
    __shared__ float xT[134 * LDK2];    // 36.4 KB gather tile
    __shared__ float x2T[128 * LDK2];   // 34.8 KB x2 [c2][k]
    int t = threadIdx.x;
    int ogA = t >> 4, kgA = t & 15;    // A: 32 x 16 -> 4o x 4k
    int o0A = ogA * 4, k0A = kgA * 4;
    int ogB = t >> 2, kgB = t & 3;     // B: 128 x 4 -> 4o x 16k
    int o0B = ogB * 4, k0B = kgB * 16;
    float lsB[4] = {0.f, 0.f, 0.f, 0.f}, lqB[4] = {0.f, 0.f, 0.f, 0.f};
    for (int bs = blockIdx.x; bs < Bb * S2; bs += gridDim.x) {
        __syncthreads();
        s2_gatherT(t, bs, xyz1, xyz2, ni2, f1, xT);
        __syncthreads();
        // A: y2a tile
        float acc[16];
        #pragma unroll
        for (int i = 0; i < 16; ++i) acc[i] = 0.f;
        for (int c = 0; c < 134; ++c) {
            float4 wv = *(const float4*)&w2aT[c * 128 + o0A];
            float4 xv = *(const float4*)&xT[c * LDK2 + k0A];
            float ws[4] = {wv.x, wv.y, wv.z, wv.w};
            float xs[4] = {xv.x, xv.y, xv.z, xv.w};
            #pragma unroll
            for (int i = 0; i < 4; ++i)
                #pragma unroll
                for (int j = 0; j < 4; ++j)
                    acc[i * 4 + j] = fmaf(ws[i], xs[j], acc[i * 4 + j]);
        }
        float4 mam = *(const float4*)&m2a[o0A];
        float4 sam = *(const float4*)&s2a[o0A];
        float4 bam = *(const float4*)&beta2a[o0A];
        float ma[4] = {mam.x, mam.y, mam.z, mam.w};
        float sa[4] = {sam.x, sam.y, sam.z, sam.w};
        float ba[4] = {bam.x, bam.y, bam.z, bam.w};
        #pragma unroll
        for (int i = 0; i < 4; ++i) {
            float4 v;
            v.x = fmaxf((acc[i * 4 + 0] - ma[i]) * sa[i] + ba[i], 0.f);
            v.y = fmaxf((acc[i * 4 + 1] - ma[i]) * sa[i] + ba[i], 0.f);
            v.z = fmaxf((acc[i * 4 + 2] - ma[i]) * sa[i] + ba[i], 0.f);
            v.w = fmaxf((acc[i * 4 + 3] - ma[i]) * sa[i] + ba[i], 0.f);
            *(float4*)&x2T[(o0A + i) * LDK2 + k0A] = v;
        }
        __syncthreads();
        // B: y2b tile 4o x 16k; w2bT global broadcast
        float accB[64];
        #pragma unroll
        for (int i = 0; i < 64; ++i) accB[i] = 0.f;
        for (int c = 0; c < 128; ++c) {
            float4 wv = *(const float4*)&w2bT[c * 512 + o0B];
            const float* xr = &x2T[c * LDK2 + k0B];
            float4 x0 = *(const float4*)(xr);
            float4 x1 = *(const float4*)(xr + 4);
            float4 x2 = *(const float4*)(xr + 8);
            float4 x3 = *(const float4*)(xr + 12);
            float ws[4] = {wv.x, wv.y, wv.z, wv.w};
            float xs[16] = {x0.x, x0.y, x0.z, x0.w, x1.x, x1.y, x1.z, x1.w,
                            x2.x, x2.y, x2.z, x2.w, x3.x, x3.y, x3.z, x3.w};
            #pragma unroll
            for (int i = 0; i < 4; ++i)
                #pragma unroll
                for (int j = 0; j < 16; ++j)
                    accB[i * 16 + j] = fmaf(ws[i], xs[j], accB[i * 16 + j]);
        }
        float mxB[4], mnB[4];
        #pragma unroll
        for (int i = 0; i < 4; ++i) {
            mxB[i] = -1e30f; mnB[i] = 1e30f;
            #pragma unroll
            for (int j = 0; j < 16; ++j) {
                float y = accB[i * 16 + j];
                lsB[i] += y; lqB[i] += y * y;
                mxB[i] = fmaxf(mxB[i], y); mnB[i] = fminf(mnB[i], y);
            }
        }
        #pragma unroll
        for (int off = 2; off > 0; off >>= 1)
            #pragma unroll
            for (int i = 0; i < 4; ++i) {
                mxB[i] = fmaxf(mxB[i], __shfl_down(mxB[i], off));
                mnB[i] = fminf(mnB[i], __shfl_down(mnB[i], off));
            }
        if (kgB == 0) {
            *(float4*)&gmx[(size_t)bs * 512 + o0B] = make_float4(mxB[0], mxB[1], mxB[2], mxB[3]);
            *(float4*)&gmn[(size_t)bs * 512 + o0B] = make_float4(mnB[0], mnB[1], mnB[2], mnB[3]);
        }
    }
    #pragma unroll
    for (int off = 2; off > 0; off >>= 1)
        #pragma unroll
        for (int i = 0; i < 4; ++i) {
            lsB[i] += __shfl_down(lsB[i], off);
            lqB[i] += __shfl_down(lqB[i], off);
        }
    if (kgB == 0)
        #pragma unroll
        for (int i = 0; i < 4; ++i) {
            atomicAdd(&dsum[o0B + i], (double)lsB[i]);
            atomicAdd(&dsq[o0B + i], (double)lqB[i]);
        }
}

// ---------------- Stage 3 ----------------
constexpr int X3_LD = 520;  // 515 real + 5 zero pad

__global__ __launch_bounds__(512)
void k_s3(const float* __restrict__ xyz2, const float* __restrict__ f2,
          const float* __restrict__ w3, double* __restrict__ dsum,
          double* __restrict__ dsq, float* __restrict__ gmx, float* __restrict__ gmn) {
    __shared__ float xt[16 * X3_LD];  // 33.3 KB
    int b = blockIdx.x >> 3, kc = blockIdx.x & 7;
    int t = threadIdx.x;  // = o
    for (int idx = t; idx < 16 * X3_LD; idx += 512) {
        int rr = idx / X3_LD, c = idx - rr * X3_LD;
        int row = b * S2 + kc * 16 + rr;
        float v;
        if (c < 3)        v = xyz2[row * 3 + c];
        else if (c < 515) v = f2[(size_t)row * 512 + (c - 3)];
        else              v = 0.f;
        xt[idx] = v;
    }
    __syncthreads();
    float acc[16];
    #pragma unroll
    for (int rr = 0; rr < 16; ++rr) acc[rr] = 0.f;
    for (int ct = 0; ct < 16; ++ct) {
        float wr[32];
        #pragma unroll
        for (int i = 0; i < 32; ++i) wr[i] = w3[(size_t)t * 515 + ct * 32 + i];
        #pragma unroll
        for (int rr = 0; rr < 16; ++rr) {
            const float* xr = &xt[rr * X3_LD + ct * 32];
            #pragma unroll
            for (int j = 0; j < 8; ++j) {
                float4 x = *(const float4*)(xr + 4 * j);
                acc[rr] = fmaf(x.x, wr[4 * j + 0], acc[rr]);
                acc[rr] = fmaf(x.y, wr[4 * j + 1], acc[rr]);
                acc[rr] = fmaf(x.z, wr[4 * j + 2], acc[rr]);
                acc[rr] = fmaf(x.w, wr[4 * j + 3], acc[rr]);
            }
        }
    }
    {
        float wr[8];
        #pragma unroll
        for (int i = 0; i < 8; ++i) wr[i] = (i < 3) ? w3[(size_t)t * 515 + 512 + i] : 0.f;
        #pragma unroll
        for (int rr = 0; rr < 16; ++rr) {
            const float* xr = &xt[rr * X3_LD + 512];
            #pragma unroll
            for (int j = 0; j < 2; ++j) {
                float4 x = *(const float4*)(xr + 4 * j);
                acc[rr] = fmaf(x.x, wr[4 * j + 0], acc[rr]);
                acc[rr] = fmaf(x.y, wr[4 * j + 1], acc[rr]);
                acc[rr] = fmaf(x.z, wr[4 * j + 2], acc[rr]);
                acc[rr] = fmaf(x.w, wr[4 * j + 3], acc[rr]);
            }
        }
    }
    float ls = 0.f, lsq = 0.f, mxv = -1e30f, mnv = 1e30f;
    #pragma unroll
    for (int rr = 0; rr < 16; ++rr) {
        float y = acc[rr];
        ls += y; lsq += y * y;
        mxv = fmaxf(mxv, y); mnv = fminf(mnv, y);
    }
    atomicAdd(&dsum[t], (double)ls);
    atomicAdd(&dsq[t], (double)lsq);
    gmx[(size_t)blockIdx.x * 512 + t] = mxv;
    gmn[(size_t)blockIdx.x * 512 + t] = mnv;
}

__global__ void k_apply3(const float* __restrict__ gmx, const float* __restrict__ gmn,
                         const float* __restrict__ m, const float* __restrict__ s,
                         const float* __restrict__ beta, float* __restrict__ out) {
    int i = blockIdx.x * blockDim.x + threadIdx.x;
    if (i >= Bb * 512) return;
    int b = i >> 9, o = i & 511;
    float mx = -1e30f, mn = 1e30f;
    for (int ch = 0; ch < 8; ++ch) {
        mx = fmaxf(mx, gmx[(size_t)(b * 8 + ch) * 512 + o]);
        mn = fminf(mn, gmn[(size_t)(b * 8 + ch) * 512 + o]);
    }
    float sc = s[o];
    float pick = (sc >= 0.f) ? mx : mn;
    out[i] = fmaxf((pick - m[o]) * sc + beta[o], 0.f);
}

static inline size_t align256(size_t x) { return (x + 255) & ~(size_t)255; }

extern "C" void kernel_launch(void* const* d_in, const int* in_sizes, int n_in,
                              void* d_out, int out_size, void* d_ws, size_t ws_size,
                              hipStream_t stream) {
    const float* pc  = (const float*)d_in[0];
    const float* w1a = (const float*)d_in[1];
    const float* g1a = (const float*)d_in[2];
    const float* b1a = (const float*)d_in[3];
    const float* w1b = (const float*)d_in[4];
    const float* g1b = (const float*)d_in[5];
    const float* b1b = (const float*)d_in[6];
    const float* w2a = (const float*)d_in[7];
    const float* g2a = (const float*)d_in[8];
    const float* b2a = (const float*)d_in[9];
    const float* w2b = (const float*)d_in[10];
    const float* g2b = (const float*)d_in[11];
    const float* b2b = (const float*)d_in[12];
    const float* w3  = (const float*)d_in[13];
    const float* g3  = (const float*)d_in[14];
    const float* b3  = (const float*)d_in[15];
    float* out = (float*)d_out;

    char* ws = (char*)d_ws;
    size_t off = 0;
    auto alloc = [&](size_t bytes) { void* p = ws + off; off += align256(bytes); return p; };

    float* xyz   = (float*)alloc(sizeof(float) * Bb * Nn * 3);
    float* xyz1  = (float*)alloc(sizeof(float) * Bb * S1 * 3);
    float* xyz2  = (float*)alloc(sizeof(float) * Bb * S2 * 3);
    int*   ni1   = (int*)alloc(sizeof(int) * Bb * S1 * K1);
    int*   ni2   = (int*)alloc(sizeof(int) * Bb * S2 * K2);
    float* gmx1  = (float*)alloc(sizeof(float) * (size_t)Bb * S1 * 128);  // f1 after apply
    float* gmn1  = (float*)alloc(sizeof(float) * (size_t)Bb * S1 * 128);
    float* gmx2  = (float*)alloc(sizeof(float) * (size_t)Bb * S2 * 512);  // f2 after apply
    float* gmn2  = (float*)alloc(sizeof(float) * (size_t)Bb * S2 * 512);
    float* gmx3  = (float*)alloc(sizeof(float) * 256 * 512);
    float* gmn3  = (float*)alloc(sizeof(float) * 256 * 512);
    float* w2aT  = (float*)alloc(sizeof(float) * 134 * 128);
    float* w2bT  = (float*)alloc(sizeof(float) * 128 * 512);
    double* dsum = (double*)alloc(sizeof(double) * 512);
    double* dsq  = (double*)alloc(sizeof(double) * 512);
    float* m1a = (float*)alloc(sizeof(float) * 64);
    float* s1a = (float*)alloc(sizeof(float) * 64);
    float* m1b = (float*)alloc(sizeof(float) * 128);
    float* s1b = (float*)alloc(sizeof(float) * 128);
    float* m2a = (float*)alloc(sizeof(float) * 128);
    float* s2a = (float*)alloc(sizeof(float) * 128);
    float* m2b = (float*)alloc(sizeof(float) * 512);
    float* s2b = (float*)alloc(sizeof(float) * 512);
    float* m3  = (float*)alloc(sizeof(float) * 512);
    float* s3  = (float*)alloc(sizeof(float) * 512);
    float* f1 = gmx1;  // in-place apply
    float* f2 = gmx2;

    // ---- Stage 1 ----
    k_transpose<<<(Bb * Nn + 255) / 256, 256, 0, stream>>>(pc, xyz);
    k_wtrans<<<256, 256, 0, stream>>>(w2a, w2b, w2aT, w2bT);
    k_fps_fast<8><<<Bb, 256, 0, stream>>>(xyz, S1, xyz1);
    k_ballquery_w<<<(Bb * S1) / 4, 256, 0, stream>>>(xyz, xyz1, Nn, S1, K1,
                                                     (float)(0.23 * 0.23), ni1);
    k_zero_stats<<<2, 256, 0, stream>>>(dsum, dsq, 512);
    k_s1_statsA<<<2048, 256, 0, stream>>>(xyz, xyz1, ni1, w1a, dsum, dsq);
    k_finalize<<<2, 256, 0, stream>>>(dsum, dsq, g1a, m1a, s1a, 64,
                                      1.0 / ((double)Bb * S1 * K1));
    k_zero_stats<<<2, 256, 0, stream>>>(dsum, dsq, 512);
    k_s1_main<<<1024, 256, 0, stream>>>(xyz, xyz1, ni1, w1a, m1a, s1a, b1a, w1b,
                                        dsum, dsq, gmx1, gmn1);
    k_finalize<<<2, 256, 0, stream>>>(dsum, dsq, g1b, m1b, s1b, 128,
                                      1.0 / ((double)Bb * S1 * K1));
    {
        long long tot = (long long)Bb * S1 * 128;
        k_applyMM<<<(int)((tot + 255) / 256), 256, 0, stream>>>(gmx1, gmn1, m1b, s1b, b1b,
                                                                f1, tot, 128);
    }
    // ---- Stage 2 ----
    k_fps_fast<2><<<Bb, 256, 0, stream>>>(xyz1, S2, xyz2);
    k_ballquery_w<<<(Bb * S2) / 4, 256, 0, stream>>>(xyz1, xyz2, S1, S2, K2,
                                                     (float)(0.32 * 0.32), ni2);
    k_zero_stats<<<2, 256, 0, stream>>>(dsum, dsq, 512);
    k_s2_statsA<<<1024, 512, 0, stream>>>(xyz1, xyz2, ni2, f1, w2aT, dsum, dsq);
    k_finalize<<<2, 256, 0, stream>>>(dsum, dsq, g2a, m2a, s2a, 128,
                                      1.0 / ((double)Bb * S2 * K2));
    k_zero_stats<<<2, 256, 0, stream>>>(dsum, dsq, 512);
    k_s2_main<<<1024, 512, 0, stream>>>(xyz1, xyz2, ni2, f1, w2aT, m2a, s2a, b2a, w2bT,
                                        dsum, dsq, gmx2, gmn2);
    k_finalize<<<2, 256, 0, stream>>>(dsum, dsq, g2b, m2b, s2b, 512,
                                      1.0 / ((double)Bb * S2 * K2));
    {
        long long tot = (long long)Bb * S2 * 512;
        k_applyMM<<<(int)((tot + 255) / 256), 256, 0, stream>>>(gmx2, gmn2, m2b, s2b, b2b,
                                                                f2, tot, 512);
    }
    // ---- Stage 3 ----
    k_zero_stats<<<2, 256, 0, stream>>>(dsum, dsq, 512);
    k_s3<<<256, 512, 0, stream>>>(xyz2, f2, w3, dsum, dsq, gmx3, gmn3);
    k_finalize<<<2, 256, 0, stream>>>(dsum, dsq, g3, m3, s3, 512,
                                      1.0 / ((double)Bb * S2));
    k_apply3<<<(Bb * 512 + 255) / 256, 256, 0, stream>>>(gmx3, gmn3, m3, s3, b3, out);
}